// Round 1
// baseline (891.703 us; speedup 1.0000x reference)
//
#include <hip/hip_runtime.h>
#include <hip/hip_bf16.h>
#include <math.h>

#define H 64
#define FIN 512
#define COUT 40

// ---------- tiny weight transposes (run once per call, negligible) ----------
__global__ void k_transpose_win(const float* __restrict__ W, float* __restrict__ Wt) {
    int idx = blockIdx.x * blockDim.x + threadIdx.x;
    if (idx < H * FIN) {
        int h = idx >> 9;      // / 512
        int k = idx & 511;
        Wt[k * H + h] = W[idx];   // Wt[512][64]
    }
}

__global__ void k_transpose_wc(const float* __restrict__ W1, const float* __restrict__ W2,
                               const float* __restrict__ Wf, float* __restrict__ Wct) {
    int idx = blockIdx.x * blockDim.x + threadIdx.x;
    if (idx < H * H) {
        int nn = idx >> 6;
        int k = idx & 63;
        Wct[k * 192 + nn]       = W1[idx];   // Wct[64][192]
        Wct[k * 192 + 64 + nn]  = W2[idx];
        Wct[k * 192 + 128 + nn] = Wf[idx];
    }
}

// ---------- Q = x @ W_in^T + b_in ----------
__global__ __launch_bounds__(256) void k_in_gemm(
    const float* __restrict__ x, const float* __restrict__ Wt,
    const float* __restrict__ bias, float* __restrict__ Q, int n) {
    __shared__ float As[32][68];   // [k][row+pad]
    __shared__ float Bs[32][64];   // [k][h]
    int tid = threadIdx.x;
    int base = blockIdx.x * 64;
    int tx = tid & 15, ty = tid >> 4;
    float acc[4][4] = {};

    for (int kk = 0; kk < FIN; kk += 32) {
        // stage A transposed: thread loads 2 float4 along k of one row
        {
            int row = tid >> 2;
            int kc = (tid & 3) * 8;
#pragma unroll
            for (int it = 0; it < 2; ++it) {
                float4 v = make_float4(0.f, 0.f, 0.f, 0.f);
                if (base + row < n)
                    v = *(const float4*)&x[(size_t)(base + row) * FIN + kk + kc + it * 4];
                int k0 = kc + it * 4;
                As[k0 + 0][row] = v.x;
                As[k0 + 1][row] = v.y;
                As[k0 + 2][row] = v.z;
                As[k0 + 3][row] = v.w;
            }
        }
        // stage B: contiguous 2048 floats
#pragma unroll
        for (int it = 0; it < 2; ++it) {
            int idx = tid * 4 + it * 1024;
            *(float4*)&(&Bs[0][0])[idx] = *(const float4*)&Wt[kk * 64 + idx];
        }
        __syncthreads();
#pragma unroll 8
        for (int k = 0; k < 32; ++k) {
            float4 a = *(float4*)&As[k][ty * 4];
            float4 b = *(float4*)&Bs[k][tx * 4];
#pragma unroll
            for (int i = 0; i < 4; ++i) {
                float av = (i == 0) ? a.x : (i == 1) ? a.y : (i == 2) ? a.z : a.w;
                acc[i][0] += av * b.x;
                acc[i][1] += av * b.y;
                acc[i][2] += av * b.z;
                acc[i][3] += av * b.w;
            }
        }
        __syncthreads();
    }
    float4 bv = *(const float4*)&bias[tx * 4];
#pragma unroll
    for (int i = 0; i < 4; ++i) {
        int r = base + ty * 4 + i;
        if (r < n) {
            float4 v;
            v.x = acc[i][0] + bv.x;
            v.y = acc[i][1] + bv.y;
            v.z = acc[i][2] + bv.z;
            v.w = acc[i][3] + bv.w;
            *(float4*)&Q[(size_t)r * H + tx * 4] = v;
        }
    }
}

// ---------- h3 = Q@W1^T, h4 = Q@W2^T, hq = relu(Q@Wf^T) ----------
__global__ __launch_bounds__(256) void k_layer_gemm(
    const float* __restrict__ Q, const float* __restrict__ Wct,
    float* __restrict__ h3, float* __restrict__ h4, float* __restrict__ hq, int n) {
    __shared__ float Qs[64][68];
    int tid = threadIdx.x;
    int base = blockIdx.x * 64;
#pragma unroll
    for (int it = 0; it < 4; ++it) {
        int idx = tid * 4 + it * 1024;
        int row = idx >> 6, col = idx & 63;
        float4 v = make_float4(0.f, 0.f, 0.f, 0.f);
        if (base + row < n) v = *(const float4*)&Q[(size_t)(base + row) * H + col];
        *(float4*)&Qs[row][col] = v;
    }
    __syncthreads();
    int tx = tid & 15, ty = tid >> 4;
    float acc[3][4][4] = {};
#pragma unroll 4
    for (int k = 0; k < 64; ++k) {
        float a[4];
#pragma unroll
        for (int i = 0; i < 4; ++i) a[i] = Qs[ty * 4 + i][k];
#pragma unroll
        for (int j = 0; j < 3; ++j) {
            float4 b = *(const float4*)&Wct[k * 192 + j * 64 + tx * 4];
#pragma unroll
            for (int i = 0; i < 4; ++i) {
                acc[j][i][0] += a[i] * b.x;
                acc[j][i][1] += a[i] * b.y;
                acc[j][i][2] += a[i] * b.z;
                acc[j][i][3] += a[i] * b.w;
            }
        }
    }
#pragma unroll
    for (int i = 0; i < 4; ++i) {
        int r = base + ty * 4 + i;
        if (r < n) {
            size_t off = (size_t)r * H + tx * 4;
            float4 v3, v4, vf;
            v3.x = acc[0][i][0]; v3.y = acc[0][i][1]; v3.z = acc[0][i][2]; v3.w = acc[0][i][3];
            v4.x = acc[1][i][0]; v4.y = acc[1][i][1]; v4.z = acc[1][i][2]; v4.w = acc[1][i][3];
            vf.x = fmaxf(acc[2][i][0], 0.f);
            vf.y = fmaxf(acc[2][i][1], 0.f);
            vf.z = fmaxf(acc[2][i][2], 0.f);
            vf.w = fmaxf(acc[2][i][3], 0.f);
            *(float4*)&h3[off] = v3;
            *(float4*)&h4[off] = v4;
            *(float4*)&hq[off] = vf;
        }
    }
}

// ---------- per-edge gate + scatter: hq[c] += s*h3[r] - (1-s)*h4[r] ----------
__global__ __launch_bounds__(256) void k_edge(
    const int* __restrict__ ei, const float* __restrict__ h3,
    const float* __restrict__ h4, float* __restrict__ hq, int nE) {
    int lane = threadIdx.x & 63;
    int wid = (blockIdx.x * blockDim.x + threadIdx.x) >> 6;
    int nw = (gridDim.x * blockDim.x) >> 6;
    for (int e = wid; e < nE; e += nw) {
        int r = ei[e];
        int c = ei[nE + e];
        float h3r = h3[(size_t)r * H + lane];
        float h4c = h4[(size_t)c * H + lane];
        float h4r = h4[(size_t)r * H + lane];
        float d = h3r * h4c;
#pragma unroll
        for (int off = 32; off; off >>= 1) d += __shfl_xor(d, off, 64);
        float s = 1.0f / (1.0f + __expf(d));   // sigmoid(-d)
        float msg = s * h3r - (1.0f - s) * h4r;
        atomicAdd(&hq[(size_t)c * H + lane], msg);
    }
}

// ---------- Q = hq / max(||hq||_2, 1e-12) ----------
__global__ __launch_bounds__(256) void k_norm(
    const float* __restrict__ hq, float* __restrict__ Q, int n) {
    int lane = threadIdx.x & 63;
    int w = threadIdx.x >> 6;
    int wid = blockIdx.x * 4 + w;
    int nw = gridDim.x * 4;
    for (int r = wid; r < n; r += nw) {
        float v = hq[(size_t)r * H + lane];
        float ss = v * v;
#pragma unroll
        for (int off = 32; off; off >>= 1) ss += __shfl_xor(ss, off, 64);
        float inv = 1.0f / fmaxf(sqrtf(ss), 1e-12f);
        Q[(size_t)r * H + lane] = v * inv;
    }
}

// ---------- logits = Q@W_out^T + b_out ; out = log_softmax ----------
__global__ __launch_bounds__(256) void k_out(
    const float* __restrict__ Q, const float* __restrict__ W_out,
    const float* __restrict__ b_out, float* __restrict__ out, int n) {
    __shared__ float Wt[H][COUT];   // Wt[k][c]
    __shared__ float qrow[4][H];
    int tid = threadIdx.x;
    for (int idx = tid; idx < H * COUT; idx += 256) {
        int k = idx / COUT, c = idx % COUT;
        Wt[k][c] = W_out[c * H + k];
    }
    __syncthreads();
    int lane = tid & 63;
    int w = tid >> 6;
    float bb = (lane < COUT) ? b_out[lane] : 0.f;
    int wid = blockIdx.x * 4 + w;
    int nw = gridDim.x * 4;
    for (int r = wid; r < n; r += nw) {
        float q = Q[(size_t)r * H + lane];
        qrow[w][lane] = q;
        float logit = -3.0e38f;
        if (lane < COUT) {
            float a = bb;
#pragma unroll 8
            for (int k = 0; k < H; ++k) a += qrow[w][k] * Wt[k][lane];
            logit = a;
        }
        float m = logit;
#pragma unroll
        for (int off = 32; off; off >>= 1) m = fmaxf(m, __shfl_xor(m, off, 64));
        float ex = (lane < COUT) ? __expf(logit - m) : 0.f;
#pragma unroll
        for (int off = 32; off; off >>= 1) ex += __shfl_xor(ex, off, 64);
        if (lane < COUT) out[(size_t)r * COUT + lane] = (logit - m) - logf(ex);
    }
}

extern "C" void kernel_launch(void* const* d_in, const int* in_sizes, int n_in,
                              void* d_out, int out_size, void* d_ws, size_t ws_size,
                              hipStream_t stream) {
    const float* x     = (const float*)d_in[0];
    const int*   ei    = (const int*)d_in[1];
    const float* W_in  = (const float*)d_in[2];
    const float* b_in  = (const float*)d_in[3];
    const float* W1_0  = (const float*)d_in[4];
    const float* W2_0  = (const float*)d_in[5];
    const float* Wf_0  = (const float*)d_in[6];
    const float* W1_1  = (const float*)d_in[7];
    const float* W2_1  = (const float*)d_in[8];
    const float* Wf_1  = (const float*)d_in[9];
    const float* W_out = (const float*)d_in[10];
    const float* b_out = (const float*)d_in[11];
    float* out = (float*)d_out;

    int N = in_sizes[0] / FIN;
    int E = in_sizes[1] / 2;

    float* ws    = (float*)d_ws;
    float* Wt_in = ws;                       // 512*64  = 32768
    float* Wct0  = Wt_in + 32768;            // 64*192  = 12288
    float* Wct1  = Wct0 + 12288;             // 12288
    float* Q     = Wct1 + 12288;
    float* h3    = Q  + (size_t)N * H;
    float* h4    = h3 + (size_t)N * H;
    float* hq    = h4 + (size_t)N * H;

    k_transpose_win<<<(H * FIN + 255) / 256, 256, 0, stream>>>(W_in, Wt_in);
    k_transpose_wc<<<(H * H + 255) / 256, 256, 0, stream>>>(W1_0, W2_0, Wf_0, Wct0);
    k_transpose_wc<<<(H * H + 255) / 256, 256, 0, stream>>>(W1_1, W2_1, Wf_1, Wct1);

    int gm = (N + 63) / 64;
    k_in_gemm<<<gm, 256, 0, stream>>>(x, Wt_in, b_in, Q, N);

    for (int l = 0; l < 2; ++l) {
        const float* Wct = l ? Wct1 : Wct0;
        k_layer_gemm<<<gm, 256, 0, stream>>>(Q, Wct, h3, h4, hq, N);
        k_edge<<<2048, 256, 0, stream>>>(ei, h3, h4, hq, E);
        k_norm<<<1024, 256, 0, stream>>>(hq, Q, N);
    }
    k_out<<<1024, 256, 0, stream>>>(Q, W_out, b_out, out, N);
}

// Round 2
// 805.021 us; speedup vs baseline: 1.1077x; 1.1077x over previous
//
#include <hip/hip_runtime.h>
#include <hip/hip_bf16.h>
#include <math.h>

#define H 64
#define FIN 512
#define COUT 40

// ---------- tiny weight transposes ----------
__global__ void k_transpose_win(const float* __restrict__ W, float* __restrict__ Wt) {
    int idx = blockIdx.x * blockDim.x + threadIdx.x;
    if (idx < H * FIN) {
        int h = idx >> 9;
        int k = idx & 511;
        Wt[k * H + h] = W[idx];
    }
}

__global__ void k_transpose_wc(const float* __restrict__ W1, const float* __restrict__ W2,
                               const float* __restrict__ Wf, float* __restrict__ Wct) {
    int idx = blockIdx.x * blockDim.x + threadIdx.x;
    if (idx < H * H) {
        int nn = idx >> 6;
        int k = idx & 63;
        Wct[k * 192 + nn]       = W1[idx];
        Wct[k * 192 + 64 + nn]  = W2[idx];
        Wct[k * 192 + 128 + nn] = Wf[idx];
    }
}

// ---------- CSR build ----------
__global__ void k_zero(int* __restrict__ p, int n) {
    int i = blockIdx.x * blockDim.x + threadIdx.x;
    if (i < n) p[i] = 0;
}

__global__ void k_hist(const int* __restrict__ ei, int* __restrict__ deg, int nE) {
    int e = blockIdx.x * blockDim.x + threadIdx.x;
    if (e < nE) atomicAdd(&deg[ei[nE + e]], 1);
}

// per-block (1024 elems) exclusive scan; epos gets within-block exclusive prefix
__global__ __launch_bounds__(256) void k_scan1(const int* __restrict__ deg, int* __restrict__ epos,
                                               int* __restrict__ blocksum, int n) {
    __shared__ int tmp[256];
    int t = threadIdx.x;
    int base = blockIdx.x * 1024 + t * 4;
    int v[4]; int s = 0;
#pragma unroll
    for (int i = 0; i < 4; ++i) { v[i] = (base + i < n) ? deg[base + i] : 0; s += v[i]; }
    tmp[t] = s;
    __syncthreads();
    int incl = s;
    for (int off = 1; off < 256; off <<= 1) {
        int y = (t >= off) ? tmp[t - off] : 0;
        __syncthreads();
        incl += y;
        tmp[t] = incl;
        __syncthreads();
    }
    if (t == 255) blocksum[blockIdx.x] = incl;
    int run = incl - s;
#pragma unroll
    for (int i = 0; i < 4; ++i) { if (base + i < n) epos[base + i] = run; run += v[i]; }
}

__global__ __launch_bounds__(256) void k_scan2(const int* __restrict__ blocksum,
                                               int* __restrict__ blockoff, int nb) {
    __shared__ int tmp[256];
    int t = threadIdx.x;
    int s = (t < nb) ? blocksum[t] : 0;
    tmp[t] = s;
    __syncthreads();
    int incl = s;
    for (int off = 1; off < 256; off <<= 1) {
        int y = (t >= off) ? tmp[t - off] : 0;
        __syncthreads();
        incl += y;
        tmp[t] = incl;
        __syncthreads();
    }
    if (t < nb) blockoff[t] = incl - s;
}

__global__ __launch_bounds__(256) void k_scan3(int* __restrict__ epos, const int* __restrict__ blockoff,
                                               int* __restrict__ cursor, int n, int nE) {
    int b = blockIdx.x;
    int off = blockoff[b];
    int base = b * 1024 + threadIdx.x * 4;
#pragma unroll
    for (int i = 0; i < 4; ++i) {
        if (base + i < n) {
            int p = epos[base + i] + off;
            epos[base + i] = p;     // epos doubles as rowptr
            cursor[base + i] = p;
        }
    }
    if (b == 0 && threadIdx.x == 0) epos[n] = nE;
}

__global__ void k_scatter(const int* __restrict__ ei, int* __restrict__ cursor,
                          int* __restrict__ srcidx, int nE) {
    int e = blockIdx.x * blockDim.x + threadIdx.x;
    if (e < nE) {
        int c = ei[nE + e];
        int p = atomicAdd(&cursor[c], 1);
        srcidx[p] = ei[e];
    }
}

// ---------- Q = x @ W_in^T + b_in ----------
__global__ __launch_bounds__(256) void k_in_gemm(
    const float* __restrict__ x, const float* __restrict__ Wt,
    const float* __restrict__ bias, float* __restrict__ Q, int n) {
    __shared__ float As[32][68];
    __shared__ float Bs[32][64];
    int tid = threadIdx.x;
    int base = blockIdx.x * 64;
    int tx = tid & 15, ty = tid >> 4;
    float acc[4][4] = {};

    for (int kk = 0; kk < FIN; kk += 32) {
        {
            int row = tid >> 2;
            int kc = (tid & 3) * 8;
#pragma unroll
            for (int it = 0; it < 2; ++it) {
                float4 v = make_float4(0.f, 0.f, 0.f, 0.f);
                if (base + row < n)
                    v = *(const float4*)&x[(size_t)(base + row) * FIN + kk + kc + it * 4];
                int k0 = kc + it * 4;
                As[k0 + 0][row] = v.x;
                As[k0 + 1][row] = v.y;
                As[k0 + 2][row] = v.z;
                As[k0 + 3][row] = v.w;
            }
        }
#pragma unroll
        for (int it = 0; it < 2; ++it) {
            int idx = tid * 4 + it * 1024;
            *(float4*)&(&Bs[0][0])[idx] = *(const float4*)&Wt[kk * 64 + idx];
        }
        __syncthreads();
#pragma unroll 8
        for (int k = 0; k < 32; ++k) {
            float4 a = *(float4*)&As[k][ty * 4];
            float4 b = *(float4*)&Bs[k][tx * 4];
#pragma unroll
            for (int i = 0; i < 4; ++i) {
                float av = (i == 0) ? a.x : (i == 1) ? a.y : (i == 2) ? a.z : a.w;
                acc[i][0] += av * b.x;
                acc[i][1] += av * b.y;
                acc[i][2] += av * b.z;
                acc[i][3] += av * b.w;
            }
        }
        __syncthreads();
    }
    float4 bv = *(const float4*)&bias[tx * 4];
#pragma unroll
    for (int i = 0; i < 4; ++i) {
        int r = base + ty * 4 + i;
        if (r < n) {
            float4 v;
            v.x = acc[i][0] + bv.x;
            v.y = acc[i][1] + bv.y;
            v.z = acc[i][2] + bv.z;
            v.w = acc[i][3] + bv.w;
            *(float4*)&Q[(size_t)r * H + tx * 4] = v;
        }
    }
}

// ---------- h3 = Q@W1^T, h4 = Q@W2^T, hloop = relu(Q@Wf^T) ----------
__global__ __launch_bounds__(256) void k_layer_gemm(
    const float* __restrict__ Q, const float* __restrict__ Wct,
    float* __restrict__ h3, float* __restrict__ h4, float* __restrict__ hloop, int n) {
    __shared__ float Qs[64][68];
    int tid = threadIdx.x;
    int base = blockIdx.x * 64;
#pragma unroll
    for (int it = 0; it < 4; ++it) {
        int idx = tid * 4 + it * 1024;
        int row = idx >> 6, col = idx & 63;
        float4 v = make_float4(0.f, 0.f, 0.f, 0.f);
        if (base + row < n) v = *(const float4*)&Q[(size_t)(base + row) * H + col];
        *(float4*)&Qs[row][col] = v;
    }
    __syncthreads();
    int tx = tid & 15, ty = tid >> 4;
    float acc[3][4][4] = {};
#pragma unroll 4
    for (int k = 0; k < 64; ++k) {
        float a[4];
#pragma unroll
        for (int i = 0; i < 4; ++i) a[i] = Qs[ty * 4 + i][k];
#pragma unroll
        for (int j = 0; j < 3; ++j) {
            float4 b = *(const float4*)&Wct[k * 192 + j * 64 + tx * 4];
#pragma unroll
            for (int i = 0; i < 4; ++i) {
                acc[j][i][0] += a[i] * b.x;
                acc[j][i][1] += a[i] * b.y;
                acc[j][i][2] += a[i] * b.z;
                acc[j][i][3] += a[i] * b.w;
            }
        }
    }
#pragma unroll
    for (int i = 0; i < 4; ++i) {
        int r = base + ty * 4 + i;
        if (r < n) {
            size_t off = (size_t)r * H + tx * 4;
            float4 v3, v4, vf;
            v3.x = acc[0][i][0]; v3.y = acc[0][i][1]; v3.z = acc[0][i][2]; v3.w = acc[0][i][3];
            v4.x = acc[1][i][0]; v4.y = acc[1][i][1]; v4.z = acc[1][i][2]; v4.w = acc[1][i][3];
            vf.x = fmaxf(acc[2][i][0], 0.f);
            vf.y = fmaxf(acc[2][i][1], 0.f);
            vf.z = fmaxf(acc[2][i][2], 0.f);
            vf.w = fmaxf(acc[2][i][3], 0.f);
            *(float4*)&h3[off] = v3;
            *(float4*)&h4[off] = v4;
            *(float4*)&hloop[off] = vf;
        }
    }
}

// ---------- CSR gather aggregation + fused L2-normalize ----------
// Q[c] = normalize( hloop[c] + sum_{e: col=c} s_e*h3[r_e] - (1-s_e)*h4[r_e] )
__global__ __launch_bounds__(256) void k_agg(
    const int* __restrict__ rowptr, const int* __restrict__ srcidx,
    const float* __restrict__ h3, const float* __restrict__ h4,
    const float* __restrict__ hloop, float* __restrict__ Q, int n) {
    int lane = threadIdx.x & 63;
    int c = blockIdx.x * 4 + (threadIdx.x >> 6);
    if (c >= n) return;
    float h4c = h4[(size_t)c * H + lane];
    float acc = hloop[(size_t)c * H + lane];
    int k0 = rowptr[c], k1 = rowptr[c + 1];
    if (k0 < k1) {
        int r = srcidx[k0];
        float h3r = h3[(size_t)r * H + lane];
        float h4r = h4[(size_t)r * H + lane];
        for (int k = k0; k < k1; ++k) {
            // prefetch next edge while reducing current
            int rn = 0; float h3n = 0.f, h4n = 0.f;
            if (k + 1 < k1) {
                rn = srcidx[k + 1];
                h3n = h3[(size_t)rn * H + lane];
                h4n = h4[(size_t)rn * H + lane];
            }
            float d = h3r * h4c;
#pragma unroll
            for (int off = 32; off; off >>= 1) d += __shfl_xor(d, off, 64);
            float s = 1.0f / (1.0f + __expf(d));   // sigmoid(-d)
            acc += s * h3r - (1.0f - s) * h4r;
            h3r = h3n; h4r = h4n;
        }
    }
    float ss = acc * acc;
#pragma unroll
    for (int off = 32; off; off >>= 1) ss += __shfl_xor(ss, off, 64);
    float inv = 1.0f / fmaxf(sqrtf(ss), 1e-12f);
    Q[(size_t)c * H + lane] = acc * inv;
}

// ---------- logits = Q@W_out^T + b_out ; out = log_softmax ----------
__global__ __launch_bounds__(256) void k_out(
    const float* __restrict__ Q, const float* __restrict__ W_out,
    const float* __restrict__ b_out, float* __restrict__ out, int n) {
    __shared__ float Wt[H][COUT];
    __shared__ float qrow[4][H];
    int tid = threadIdx.x;
    for (int idx = tid; idx < H * COUT; idx += 256) {
        int k = idx / COUT, c = idx % COUT;
        Wt[k][c] = W_out[c * H + k];
    }
    __syncthreads();
    int lane = tid & 63;
    int w = tid >> 6;
    float bb = (lane < COUT) ? b_out[lane] : 0.f;
    int wid = blockIdx.x * 4 + w;
    int nw = gridDim.x * 4;
    for (int r = wid; r < n; r += nw) {
        float q = Q[(size_t)r * H + lane];
        qrow[w][lane] = q;
        float logit = -3.0e38f;
        if (lane < COUT) {
            float a = bb;
#pragma unroll 8
            for (int k = 0; k < H; ++k) a += qrow[w][k] * Wt[k][lane];
            logit = a;
        }
        float m = logit;
#pragma unroll
        for (int off = 32; off; off >>= 1) m = fmaxf(m, __shfl_xor(m, off, 64));
        float ex = (lane < COUT) ? __expf(logit - m) : 0.f;
#pragma unroll
        for (int off = 32; off; off >>= 1) ex += __shfl_xor(ex, off, 64);
        if (lane < COUT) out[(size_t)r * COUT + lane] = (logit - m) - logf(ex);
    }
}

extern "C" void kernel_launch(void* const* d_in, const int* in_sizes, int n_in,
                              void* d_out, int out_size, void* d_ws, size_t ws_size,
                              hipStream_t stream) {
    const float* x     = (const float*)d_in[0];
    const int*   ei    = (const int*)d_in[1];
    const float* W_in  = (const float*)d_in[2];
    const float* b_in  = (const float*)d_in[3];
    const float* W1_0  = (const float*)d_in[4];
    const float* W2_0  = (const float*)d_in[5];
    const float* Wf_0  = (const float*)d_in[6];
    const float* W1_1  = (const float*)d_in[7];
    const float* W2_1  = (const float*)d_in[8];
    const float* Wf_1  = (const float*)d_in[9];
    const float* W_out = (const float*)d_in[10];
    const float* b_out = (const float*)d_in[11];
    float* out = (float*)d_out;

    int N = in_sizes[0] / FIN;
    int E = in_sizes[1] / 2;

    float* ws    = (float*)d_ws;
    float* Wt_in = ws;                       // 32768
    float* Wct0  = Wt_in + 32768;            // 12288
    float* Wct1  = Wct0 + 12288;             // 12288
    float* Q     = Wct1 + 12288;
    float* h3    = Q  + (size_t)N * H;
    float* h4    = h3 + (size_t)N * H;
    float* hloop = h4 + (size_t)N * H;
    int* rowptr  = (int*)(hloop + (size_t)N * H);   // N+1
    int* deg     = rowptr + (N + 2);                // N (also scratch)
    int* cursor  = deg + N;                         // N
    int* srcidx  = cursor + N;                      // E
    int* blocksum = srcidx + E;                     // 256
    int* blockoff = blocksum + 256;                 // 256

    // weight prep
    k_transpose_win<<<(H * FIN + 255) / 256, 256, 0, stream>>>(W_in, Wt_in);
    k_transpose_wc<<<(H * H + 255) / 256, 256, 0, stream>>>(W1_0, W2_0, Wf_0, Wct0);
    k_transpose_wc<<<(H * H + 255) / 256, 256, 0, stream>>>(W1_1, W2_1, Wf_1, Wct1);

    // CSR build (by destination), reused for both layers
    int nb = (N + 1023) / 1024;
    k_zero<<<(N + 255) / 256, 256, 0, stream>>>(deg, N);
    k_hist<<<(E + 255) / 256, 256, 0, stream>>>(ei, deg, E);
    k_scan1<<<nb, 256, 0, stream>>>(deg, rowptr, blocksum, N);
    k_scan2<<<1, 256, 0, stream>>>(blocksum, blockoff, nb);
    k_scan3<<<nb, 256, 0, stream>>>(rowptr, blockoff, cursor, N, E);
    k_scatter<<<(E + 255) / 256, 256, 0, stream>>>(ei, cursor, srcidx, E);

    int gm = (N + 63) / 64;
    k_in_gemm<<<gm, 256, 0, stream>>>(x, Wt_in, b_in, Q, N);

    for (int l = 0; l < 2; ++l) {
        const float* Wct = l ? Wct1 : Wct0;
        k_layer_gemm<<<gm, 256, 0, stream>>>(Q, Wct, h3, h4, hloop, N);
        k_agg<<<(N + 3) / 4, 256, 0, stream>>>(rowptr, srcidx, h3, h4, hloop, Q, N);
    }
    k_out<<<1024, 256, 0, stream>>>(Q, W_out, b_out, out, N);
}

// Round 3
// 660.577 us; speedup vs baseline: 1.3499x; 1.2187x over previous
//
#include <hip/hip_runtime.h>
#include <hip/hip_bf16.h>
#include <math.h>

#define H 64
#define FIN 512
#define COUT 40

// ---------- tiny weight transposes ----------
__global__ void k_transpose_win(const float* __restrict__ W, float* __restrict__ Wt) {
    int idx = blockIdx.x * blockDim.x + threadIdx.x;
    if (idx < H * FIN) {
        int h = idx >> 9;
        int k = idx & 511;
        Wt[k * H + h] = W[idx];
    }
}

__global__ void k_transpose_wc(const float* __restrict__ W1, const float* __restrict__ W2,
                               const float* __restrict__ Wf, float* __restrict__ Wct) {
    int idx = blockIdx.x * blockDim.x + threadIdx.x;
    if (idx < H * H) {
        int nn = idx >> 6;
        int k = idx & 63;
        Wct[k * 192 + nn]       = W1[idx];
        Wct[k * 192 + 64 + nn]  = W2[idx];
        Wct[k * 192 + 128 + nn] = Wf[idx];
    }
}

// ---------- CSR build ----------
__global__ void k_zero(int* __restrict__ p, int n) {
    int i = blockIdx.x * blockDim.x + threadIdx.x;
    if (i < n) p[i] = 0;
}

__global__ void k_hist(const int* __restrict__ ei, int* __restrict__ deg, int nE) {
    int e = blockIdx.x * blockDim.x + threadIdx.x;
    if (e < nE) atomicAdd(&deg[ei[nE + e]], 1);
}

__global__ __launch_bounds__(256) void k_scan1(const int* __restrict__ deg, int* __restrict__ epos,
                                               int* __restrict__ blocksum, int n) {
    __shared__ int tmp[256];
    int t = threadIdx.x;
    int base = blockIdx.x * 1024 + t * 4;
    int v[4]; int s = 0;
#pragma unroll
    for (int i = 0; i < 4; ++i) { v[i] = (base + i < n) ? deg[base + i] : 0; s += v[i]; }
    tmp[t] = s;
    __syncthreads();
    int incl = s;
    for (int off = 1; off < 256; off <<= 1) {
        int y = (t >= off) ? tmp[t - off] : 0;
        __syncthreads();
        incl += y;
        tmp[t] = incl;
        __syncthreads();
    }
    if (t == 255) blocksum[blockIdx.x] = incl;
    int run = incl - s;
#pragma unroll
    for (int i = 0; i < 4; ++i) { if (base + i < n) epos[base + i] = run; run += v[i]; }
}

__global__ __launch_bounds__(256) void k_scan2(const int* __restrict__ blocksum,
                                               int* __restrict__ blockoff, int nb) {
    __shared__ int tmp[256];
    int t = threadIdx.x;
    int s = (t < nb) ? blocksum[t] : 0;
    tmp[t] = s;
    __syncthreads();
    int incl = s;
    for (int off = 1; off < 256; off <<= 1) {
        int y = (t >= off) ? tmp[t - off] : 0;
        __syncthreads();
        incl += y;
        tmp[t] = incl;
        __syncthreads();
    }
    if (t < nb) blockoff[t] = incl - s;
}

__global__ __launch_bounds__(256) void k_scan3(int* __restrict__ epos, const int* __restrict__ blockoff,
                                               int* __restrict__ cursor, int n, int nE) {
    int b = blockIdx.x;
    int off = blockoff[b];
    int base = b * 1024 + threadIdx.x * 4;
#pragma unroll
    for (int i = 0; i < 4; ++i) {
        if (base + i < n) {
            int p = epos[base + i] + off;
            epos[base + i] = p;
            cursor[base + i] = p;
        }
    }
    if (b == 0 && threadIdx.x == 0) epos[n] = nE;
}

__global__ void k_scatter(const int* __restrict__ ei, int* __restrict__ cursor,
                          int* __restrict__ srcidx, int nE) {
    int e = blockIdx.x * blockDim.x + threadIdx.x;
    if (e < nE) {
        int c = ei[nE + e];
        int p = atomicAdd(&cursor[c], 1);
        srcidx[p] = ei[e];
    }
}

// ---------- Q = x @ W_in^T + b_in ----------
__global__ __launch_bounds__(256) void k_in_gemm(
    const float* __restrict__ x, const float* __restrict__ Wt,
    const float* __restrict__ bias, float* __restrict__ Q, int n) {
    __shared__ float As[32][68];
    __shared__ float Bs[32][64];
    int tid = threadIdx.x;
    int base = blockIdx.x * 64;
    int tx = tid & 15, ty = tid >> 4;
    float acc[4][4] = {};

    for (int kk = 0; kk < FIN; kk += 32) {
        {
            int row = tid >> 2;
            int kc = (tid & 3) * 8;
#pragma unroll
            for (int it = 0; it < 2; ++it) {
                float4 v = make_float4(0.f, 0.f, 0.f, 0.f);
                if (base + row < n)
                    v = *(const float4*)&x[(size_t)(base + row) * FIN + kk + kc + it * 4];
                int k0 = kc + it * 4;
                As[k0 + 0][row] = v.x;
                As[k0 + 1][row] = v.y;
                As[k0 + 2][row] = v.z;
                As[k0 + 3][row] = v.w;
            }
        }
#pragma unroll
        for (int it = 0; it < 2; ++it) {
            int idx = tid * 4 + it * 1024;
            *(float4*)&(&Bs[0][0])[idx] = *(const float4*)&Wt[kk * 64 + idx];
        }
        __syncthreads();
#pragma unroll 8
        for (int k = 0; k < 32; ++k) {
            float4 a = *(float4*)&As[k][ty * 4];
            float4 b = *(float4*)&Bs[k][tx * 4];
#pragma unroll
            for (int i = 0; i < 4; ++i) {
                float av = (i == 0) ? a.x : (i == 1) ? a.y : (i == 2) ? a.z : a.w;
                acc[i][0] += av * b.x;
                acc[i][1] += av * b.y;
                acc[i][2] += av * b.z;
                acc[i][3] += av * b.w;
            }
        }
        __syncthreads();
    }
    float4 bv = *(const float4*)&bias[tx * 4];
#pragma unroll
    for (int i = 0; i < 4; ++i) {
        int r = base + ty * 4 + i;
        if (r < n) {
            float4 v;
            v.x = acc[i][0] + bv.x;
            v.y = acc[i][1] + bv.y;
            v.z = acc[i][2] + bv.z;
            v.w = acc[i][3] + bv.w;
            *(float4*)&Q[(size_t)r * H + tx * 4] = v;
        }
    }
}

// ---------- h3 = Q@W1^T, h4 = Q@W2^T, hloop = relu(Q@Wf^T) ----------
__global__ __launch_bounds__(256) void k_layer_gemm(
    const float* __restrict__ Q, const float* __restrict__ Wct,
    float* __restrict__ h3, float* __restrict__ h4, float* __restrict__ hloop, int n) {
    __shared__ float Qs[64][68];
    int tid = threadIdx.x;
    int base = blockIdx.x * 64;
#pragma unroll
    for (int it = 0; it < 4; ++it) {
        int idx = tid * 4 + it * 1024;
        int row = idx >> 6, col = idx & 63;
        float4 v = make_float4(0.f, 0.f, 0.f, 0.f);
        if (base + row < n) v = *(const float4*)&Q[(size_t)(base + row) * H + col];
        *(float4*)&Qs[row][col] = v;
    }
    __syncthreads();
    int tx = tid & 15, ty = tid >> 4;
    float acc[3][4][4] = {};
#pragma unroll 4
    for (int k = 0; k < 64; ++k) {
        float a[4];
#pragma unroll
        for (int i = 0; i < 4; ++i) a[i] = Qs[ty * 4 + i][k];
#pragma unroll
        for (int j = 0; j < 3; ++j) {
            float4 b = *(const float4*)&Wct[k * 192 + j * 64 + tx * 4];
#pragma unroll
            for (int i = 0; i < 4; ++i) {
                acc[j][i][0] += a[i] * b.x;
                acc[j][i][1] += a[i] * b.y;
                acc[j][i][2] += a[i] * b.z;
                acc[j][i][3] += a[i] * b.w;
            }
        }
    }
#pragma unroll
    for (int i = 0; i < 4; ++i) {
        int r = base + ty * 4 + i;
        if (r < n) {
            size_t off = (size_t)r * H + tx * 4;
            float4 v3, v4, vf;
            v3.x = acc[0][i][0]; v3.y = acc[0][i][1]; v3.z = acc[0][i][2]; v3.w = acc[0][i][3];
            v4.x = acc[1][i][0]; v4.y = acc[1][i][1]; v4.z = acc[1][i][2]; v4.w = acc[1][i][3];
            vf.x = fmaxf(acc[2][i][0], 0.f);
            vf.y = fmaxf(acc[2][i][1], 0.f);
            vf.z = fmaxf(acc[2][i][2], 0.f);
            vf.w = fmaxf(acc[2][i][3], 0.f);
            *(float4*)&h3[off] = v3;
            *(float4*)&h4[off] = v4;
            *(float4*)&hloop[off] = vf;
        }
    }
}

// ---------- CSR gather aggregation, 4 edges/wave, float4 lanes ----------
// lane = q*16 + j : edge slot q (0..3), channel group j (channels j*4..j*4+3)
// Q[c] = normalize( hloop[c] + sum_e s_e*h3[r_e] - (1-s_e)*h4[r_e] )
__global__ __launch_bounds__(256) void k_agg(
    const int* __restrict__ rowptr, const int* __restrict__ srcidx,
    const float* __restrict__ h3, const float* __restrict__ h4,
    const float* __restrict__ hloop, float* __restrict__ Q, int n) {
    int lane = threadIdx.x & 63;
    int c = blockIdx.x * 4 + (threadIdx.x >> 6);
    if (c >= n) return;
    int q = lane >> 4;
    int j = lane & 15;
    size_t choff = (size_t)j * 4;

    float4 h4c = *(const float4*)&h4[(size_t)c * H + choff];
    float4 acc = make_float4(0.f, 0.f, 0.f, 0.f);

    int k0 = rowptr[c], k1 = rowptr[c + 1];
    if (k0 < k1) {
        // preload batch 0
        int k = k0 + q;
        bool v = k < k1;
        int r = srcidx[v ? k : (k1 - 1)];
        float4 h3r = *(const float4*)&h3[(size_t)r * H + choff];
        float4 h4r = *(const float4*)&h4[(size_t)r * H + choff];
        if (!v) { h3r = make_float4(0.f,0.f,0.f,0.f); h4r = make_float4(0.f,0.f,0.f,0.f); }

        for (int kb = k0; kb < k1; kb += 4) {
            // prefetch next batch
            float4 h3n = make_float4(0.f,0.f,0.f,0.f);
            float4 h4n = make_float4(0.f,0.f,0.f,0.f);
            if (kb + 4 < k1) {
                int k2 = kb + 4 + q;
                bool v2 = k2 < k1;
                int r2 = srcidx[v2 ? k2 : (k1 - 1)];
                float4 a = *(const float4*)&h3[(size_t)r2 * H + choff];
                float4 b = *(const float4*)&h4[(size_t)r2 * H + choff];
                if (v2) { h3n = a; h4n = b; }
            }
            // dot over 16 lanes of this quarter
            float d = h3r.x * h4c.x + h3r.y * h4c.y + h3r.z * h4c.z + h3r.w * h4c.w;
            d += __shfl_xor(d, 1, 64);
            d += __shfl_xor(d, 2, 64);
            d += __shfl_xor(d, 4, 64);
            d += __shfl_xor(d, 8, 64);
            float s = 1.0f / (1.0f + __expf(d));   // sigmoid(-d)
            float t = 1.0f - s;
            acc.x += s * h3r.x - t * h4r.x;
            acc.y += s * h3r.y - t * h4r.y;
            acc.z += s * h3r.z - t * h4r.z;
            acc.w += s * h3r.w - t * h4r.w;
            h3r = h3n; h4r = h4n;
        }
    }
    // sum across the 4 edge slots (quarters)
    acc.x += __shfl_xor(acc.x, 16, 64);
    acc.y += __shfl_xor(acc.y, 16, 64);
    acc.z += __shfl_xor(acc.z, 16, 64);
    acc.w += __shfl_xor(acc.w, 16, 64);
    acc.x += __shfl_xor(acc.x, 32, 64);
    acc.y += __shfl_xor(acc.y, 32, 64);
    acc.z += __shfl_xor(acc.z, 32, 64);
    acc.w += __shfl_xor(acc.w, 32, 64);

    float4 hl = *(const float4*)&hloop[(size_t)c * H + choff];
    acc.x += hl.x; acc.y += hl.y; acc.z += hl.z; acc.w += hl.w;

    float ss = acc.x * acc.x + acc.y * acc.y + acc.z * acc.z + acc.w * acc.w;
    ss += __shfl_xor(ss, 1, 64);
    ss += __shfl_xor(ss, 2, 64);
    ss += __shfl_xor(ss, 4, 64);
    ss += __shfl_xor(ss, 8, 64);
    float inv = 1.0f / fmaxf(sqrtf(ss), 1e-12f);
    if (lane < 16) {
        float4 o;
        o.x = acc.x * inv; o.y = acc.y * inv; o.z = acc.z * inv; o.w = acc.w * inv;
        *(float4*)&Q[(size_t)c * H + choff] = o;
    }
}

// ---------- logits = Q@W_out^T + b_out ; out = log_softmax ----------
__global__ __launch_bounds__(256) void k_out(
    const float* __restrict__ Q, const float* __restrict__ W_out,
    const float* __restrict__ b_out, float* __restrict__ out, int n) {
    __shared__ float Wt[H][COUT];
    __shared__ float qrow[4][H];
    int tid = threadIdx.x;
    for (int idx = tid; idx < H * COUT; idx += 256) {
        int k = idx / COUT, c = idx % COUT;
        Wt[k][c] = W_out[c * H + k];
    }
    __syncthreads();
    int lane = tid & 63;
    int w = tid >> 6;
    float bb = (lane < COUT) ? b_out[lane] : 0.f;
    int wid = blockIdx.x * 4 + w;
    int nw = gridDim.x * 4;
    for (int r = wid; r < n; r += nw) {
        float q = Q[(size_t)r * H + lane];
        qrow[w][lane] = q;
        float logit = -3.0e38f;
        if (lane < COUT) {
            float a = bb;
#pragma unroll 8
            for (int k = 0; k < H; ++k) a += qrow[w][k] * Wt[k][lane];
            logit = a;
        }
        float m = logit;
#pragma unroll
        for (int off = 32; off; off >>= 1) m = fmaxf(m, __shfl_xor(m, off, 64));
        float ex = (lane < COUT) ? __expf(logit - m) : 0.f;
#pragma unroll
        for (int off = 32; off; off >>= 1) ex += __shfl_xor(ex, off, 64);
        if (lane < COUT) out[(size_t)r * COUT + lane] = (logit - m) - logf(ex);
    }
}

extern "C" void kernel_launch(void* const* d_in, const int* in_sizes, int n_in,
                              void* d_out, int out_size, void* d_ws, size_t ws_size,
                              hipStream_t stream) {
    const float* x     = (const float*)d_in[0];
    const int*   ei    = (const int*)d_in[1];
    const float* W_in  = (const float*)d_in[2];
    const float* b_in  = (const float*)d_in[3];
    const float* W1_0  = (const float*)d_in[4];
    const float* W2_0  = (const float*)d_in[5];
    const float* Wf_0  = (const float*)d_in[6];
    const float* W1_1  = (const float*)d_in[7];
    const float* W2_1  = (const float*)d_in[8];
    const float* Wf_1  = (const float*)d_in[9];
    const float* W_out = (const float*)d_in[10];
    const float* b_out = (const float*)d_in[11];
    float* out = (float*)d_out;

    int N = in_sizes[0] / FIN;
    int E = in_sizes[1] / 2;

    float* ws    = (float*)d_ws;
    float* Wt_in = ws;
    float* Wct0  = Wt_in + 32768;
    float* Wct1  = Wct0 + 12288;
    float* Q     = Wct1 + 12288;
    float* h3    = Q  + (size_t)N * H;
    float* h4    = h3 + (size_t)N * H;
    float* hloop = h4 + (size_t)N * H;
    int* rowptr  = (int*)(hloop + (size_t)N * H);
    int* deg     = rowptr + (N + 2);
    int* cursor  = deg + N;
    int* srcidx  = cursor + N;
    int* blocksum = srcidx + E;
    int* blockoff = blocksum + 256;

    k_transpose_win<<<(H * FIN + 255) / 256, 256, 0, stream>>>(W_in, Wt_in);
    k_transpose_wc<<<(H * H + 255) / 256, 256, 0, stream>>>(W1_0, W2_0, Wf_0, Wct0);
    k_transpose_wc<<<(H * H + 255) / 256, 256, 0, stream>>>(W1_1, W2_1, Wf_1, Wct1);

    int nb = (N + 1023) / 1024;
    k_zero<<<(N + 255) / 256, 256, 0, stream>>>(deg, N);
    k_hist<<<(E + 255) / 256, 256, 0, stream>>>(ei, deg, E);
    k_scan1<<<nb, 256, 0, stream>>>(deg, rowptr, blocksum, N);
    k_scan2<<<1, 256, 0, stream>>>(blocksum, blockoff, nb);
    k_scan3<<<nb, 256, 0, stream>>>(rowptr, blockoff, cursor, N, E);
    k_scatter<<<(E + 255) / 256, 256, 0, stream>>>(ei, cursor, srcidx, E);

    int gm = (N + 63) / 64;
    k_in_gemm<<<gm, 256, 0, stream>>>(x, Wt_in, b_in, Q, N);

    for (int l = 0; l < 2; ++l) {
        const float* Wct = l ? Wct1 : Wct0;
        k_layer_gemm<<<gm, 256, 0, stream>>>(Q, Wct, h3, h4, hloop, N);
        k_agg<<<(N + 3) / 4, 256, 0, stream>>>(rowptr, srcidx, h3, h4, hloop, Q, N);
    }
    k_out<<<1024, 256, 0, stream>>>(Q, W_out, b_out, out, N);
}

// Round 4
// 537.047 us; speedup vs baseline: 1.6604x; 1.2300x over previous
//
#include <hip/hip_runtime.h>
#include <hip/hip_bf16.h>
#include <math.h>

#define H 64
#define FIN 512
#define COUT 40

typedef __attribute__((ext_vector_type(8))) short bf16x8;
typedef __attribute__((ext_vector_type(4))) float f32x4;

__device__ __forceinline__ unsigned short f2bf(float f) {
    union { float f; unsigned u; } v; v.f = f;
    unsigned r = v.u + 0x7FFF + ((v.u >> 16) & 1);   // RNE
    return (unsigned short)(r >> 16);
}
__device__ __forceinline__ float bflo(unsigned u) { return __uint_as_float(u << 16); }
__device__ __forceinline__ float bfhi(unsigned u) { return __uint_as_float(u & 0xffff0000u); }

// ---------- pack W_in into bf16 B-fragments: Bp[kb][n][i] = W_in[n][kb*8+i] ----------
__global__ void k_pack_win(const float* __restrict__ W, uint4* __restrict__ Bp) {
    int t = blockIdx.x * blockDim.x + threadIdx.x;   // 4096 = 64 kb * 64 n
    if (t >= 64 * 64) return;
    int kb = t >> 6, n = t & 63;
    const float* src = &W[n * FIN + kb * 8];
    float4 a0 = *(const float4*)&src[0];
    float4 a1 = *(const float4*)&src[4];
    uint4 u;
    u.x = ((unsigned)f2bf(a0.y) << 16) | f2bf(a0.x);
    u.y = ((unsigned)f2bf(a0.w) << 16) | f2bf(a0.z);
    u.z = ((unsigned)f2bf(a1.y) << 16) | f2bf(a1.x);
    u.w = ((unsigned)f2bf(a1.w) << 16) | f2bf(a1.z);
    Bp[t] = u;
}

__global__ void k_transpose_wc(const float* __restrict__ W1, const float* __restrict__ W2,
                               const float* __restrict__ Wf, float* __restrict__ Wct) {
    int idx = blockIdx.x * blockDim.x + threadIdx.x;
    if (idx < H * H) {
        int nn = idx >> 6;
        int k = idx & 63;
        Wct[k * 192 + nn]       = W1[idx];
        Wct[k * 192 + 64 + nn]  = W2[idx];
        Wct[k * 192 + 128 + nn] = Wf[idx];
    }
}

// ---------- CSR build ----------
__global__ void k_zero(int* __restrict__ p, int n) {
    int i = blockIdx.x * blockDim.x + threadIdx.x;
    if (i < n) p[i] = 0;
}

__global__ void k_hist(const int* __restrict__ ei, int* __restrict__ deg, int nE) {
    int e = blockIdx.x * blockDim.x + threadIdx.x;
    if (e < nE) atomicAdd(&deg[ei[nE + e]], 1);
}

__global__ __launch_bounds__(256) void k_scan1(const int* __restrict__ deg, int* __restrict__ epos,
                                               int* __restrict__ blocksum, int n) {
    __shared__ int tmp[256];
    int t = threadIdx.x;
    int base = blockIdx.x * 1024 + t * 4;
    int v[4]; int s = 0;
#pragma unroll
    for (int i = 0; i < 4; ++i) { v[i] = (base + i < n) ? deg[base + i] : 0; s += v[i]; }
    tmp[t] = s;
    __syncthreads();
    int incl = s;
    for (int off = 1; off < 256; off <<= 1) {
        int y = (t >= off) ? tmp[t - off] : 0;
        __syncthreads();
        incl += y;
        tmp[t] = incl;
        __syncthreads();
    }
    if (t == 255) blocksum[blockIdx.x] = incl;
    int run = incl - s;
#pragma unroll
    for (int i = 0; i < 4; ++i) { if (base + i < n) epos[base + i] = run; run += v[i]; }
}

__global__ __launch_bounds__(256) void k_scan2(const int* __restrict__ blocksum,
                                               int* __restrict__ blockoff, int nb) {
    __shared__ int tmp[256];
    int t = threadIdx.x;
    int s = (t < nb) ? blocksum[t] : 0;
    tmp[t] = s;
    __syncthreads();
    int incl = s;
    for (int off = 1; off < 256; off <<= 1) {
        int y = (t >= off) ? tmp[t - off] : 0;
        __syncthreads();
        incl += y;
        tmp[t] = incl;
        __syncthreads();
    }
    if (t < nb) blockoff[t] = incl - s;
}

__global__ __launch_bounds__(256) void k_scan3(int* __restrict__ epos, const int* __restrict__ blockoff,
                                               int* __restrict__ cursor, int n, int nE) {
    int b = blockIdx.x;
    int off = blockoff[b];
    int base = b * 1024 + threadIdx.x * 4;
#pragma unroll
    for (int i = 0; i < 4; ++i) {
        if (base + i < n) {
            int p = epos[base + i] + off;
            epos[base + i] = p;
            cursor[base + i] = p;
        }
    }
    if (b == 0 && threadIdx.x == 0) epos[n] = nE;
}

__global__ void k_scatter(const int* __restrict__ ei, int* __restrict__ cursor,
                          int* __restrict__ srcidx, int nE) {
    int e = blockIdx.x * blockDim.x + threadIdx.x;
    if (e < nE) {
        int c = ei[nE + e];
        int p = atomicAdd(&cursor[c], 1);
        srcidx[p] = ei[e];
    }
}

// ---------- Q = x @ W_in^T + b_in  (bf16 MFMA, fp32 accumulate) ----------
// block: 256 thr = 4 waves; tile 64 rows x 64 cols; K=512 in 16 steps of 32
__global__ __launch_bounds__(256) void k_in_gemm(
    const float* __restrict__ x, const uint4* __restrict__ Bp,
    const float* __restrict__ bias, float* __restrict__ Q, int n) {
    __shared__ uint4 As4[256];   // 64 rows x 32 k bf16, granule-swizzled
    __shared__ uint4 Bs4[256];   // [kg 0..3][col 0..63] of 8 bf16
    int tid = threadIdx.x;
    int base = blockIdx.x * 64;
    int lane = tid & 63, w = tid >> 6;

    // staging assignment (A): thread -> (row srow, granule sg)
    int srow = tid >> 2;
    int sg = tid & 3;
    int sgs = sg ^ ((srow >> 1) & 3);          // swizzled granule slot
    bool rowok = (base + srow) < n;
    const float* xsrc = &x[(size_t)(base + srow) * FIN + sg * 8];

    // MFMA fragment read addresses
    int arow = 16 * w + (lane & 15);
    int ag = (lane >> 4) ^ ((arow >> 1) & 3);  // same swizzle on read
    int aidx = arow * 4 + ag;
    int kg = lane >> 4;

    f32x4 acc[4];
#pragma unroll
    for (int i = 0; i < 4; ++i) acc[i] = (f32x4){0.f, 0.f, 0.f, 0.f};

    for (int kk = 0; kk < FIN; kk += 32) {
        float4 a0 = make_float4(0.f, 0.f, 0.f, 0.f), a1 = a0;
        if (rowok) {
            a0 = *(const float4*)&xsrc[kk];
            a1 = *(const float4*)&xsrc[kk + 4];
        }
        uint4 bstage = Bp[((kk >> 3) + (tid >> 6)) * 64 + (tid & 63)];
        __syncthreads();
        {
            uint4 u;
            u.x = ((unsigned)f2bf(a0.y) << 16) | f2bf(a0.x);
            u.y = ((unsigned)f2bf(a0.w) << 16) | f2bf(a0.z);
            u.z = ((unsigned)f2bf(a1.y) << 16) | f2bf(a1.x);
            u.w = ((unsigned)f2bf(a1.w) << 16) | f2bf(a1.z);
            As4[srow * 4 + sgs] = u;
            Bs4[tid] = bstage;   // Bs4[kg*64 + col]
        }
        __syncthreads();
        bf16x8 af = *(const bf16x8*)&As4[aidx];
#pragma unroll
        for (int nt = 0; nt < 4; ++nt) {
            bf16x8 bf = *(const bf16x8*)&Bs4[kg * 64 + nt * 16 + (lane & 15)];
            acc[nt] = __builtin_amdgcn_mfma_f32_16x16x32_bf16(af, bf, acc[nt], 0, 0, 0);
        }
    }
    // epilogue: C/D mapping col=lane&15, row=(lane>>4)*4+reg
    int col0 = lane & 15, rowg = lane >> 4;
#pragma unroll
    for (int nt = 0; nt < 4; ++nt) {
        float bv = bias[nt * 16 + col0];
#pragma unroll
        for (int reg = 0; reg < 4; ++reg) {
            int r = base + 16 * w + rowg * 4 + reg;
            if (r < n) Q[(size_t)r * H + nt * 16 + col0] = acc[nt][reg] + bv;
        }
    }
}

// ---------- P = pack(bf16(Q@W1^T), bf16(Q@W2^T)), hloop = relu(Q@Wf^T) ----------
__global__ __launch_bounds__(256) void k_layer_gemm(
    const float* __restrict__ Q, const float* __restrict__ Wct,
    unsigned* __restrict__ P, float* __restrict__ hloop, int n) {
    __shared__ float Qs[64][68];
    int tid = threadIdx.x;
    int base = blockIdx.x * 64;
#pragma unroll
    for (int it = 0; it < 4; ++it) {
        int idx = tid * 4 + it * 1024;
        int row = idx >> 6, col = idx & 63;
        float4 v = make_float4(0.f, 0.f, 0.f, 0.f);
        if (base + row < n) v = *(const float4*)&Q[(size_t)(base + row) * H + col];
        *(float4*)&Qs[row][col] = v;
    }
    __syncthreads();
    int tx = tid & 15, ty = tid >> 4;
    float acc[3][4][4] = {};
#pragma unroll 4
    for (int k = 0; k < 64; ++k) {
        float a[4];
#pragma unroll
        for (int i = 0; i < 4; ++i) a[i] = Qs[ty * 4 + i][k];
#pragma unroll
        for (int j = 0; j < 3; ++j) {
            float4 b = *(const float4*)&Wct[k * 192 + j * 64 + tx * 4];
#pragma unroll
            for (int i = 0; i < 4; ++i) {
                acc[j][i][0] += a[i] * b.x;
                acc[j][i][1] += a[i] * b.y;
                acc[j][i][2] += a[i] * b.z;
                acc[j][i][3] += a[i] * b.w;
            }
        }
    }
#pragma unroll
    for (int i = 0; i < 4; ++i) {
        int r = base + ty * 4 + i;
        if (r < n) {
            size_t off = (size_t)r * H + tx * 4;
            uint4 p;
            p.x = ((unsigned)f2bf(acc[1][i][0]) << 16) | f2bf(acc[0][i][0]);
            p.y = ((unsigned)f2bf(acc[1][i][1]) << 16) | f2bf(acc[0][i][1]);
            p.z = ((unsigned)f2bf(acc[1][i][2]) << 16) | f2bf(acc[0][i][2]);
            p.w = ((unsigned)f2bf(acc[1][i][3]) << 16) | f2bf(acc[0][i][3]);
            *(uint4*)&P[off] = p;
            float4 vf;
            vf.x = fmaxf(acc[2][i][0], 0.f);
            vf.y = fmaxf(acc[2][i][1], 0.f);
            vf.z = fmaxf(acc[2][i][2], 0.f);
            vf.w = fmaxf(acc[2][i][3], 0.f);
            *(float4*)&hloop[off] = vf;
        }
    }
}

// ---------- CSR gather aggregation (packed bf16), 4 edges/wave ----------
__global__ __launch_bounds__(256) void k_agg(
    const int* __restrict__ rowptr, const int* __restrict__ srcidx,
    const unsigned* __restrict__ P, const float* __restrict__ hloop,
    float* __restrict__ Q, int n) {
    int lane = threadIdx.x & 63;
    int c = blockIdx.x * 4 + (threadIdx.x >> 6);
    if (c >= n) return;
    int q = lane >> 4;
    int j = lane & 15;
    const uint4* P4 = (const uint4*)P;

    uint4 pc = P4[(size_t)c * 16 + j];
    float4 h4c = make_float4(bfhi(pc.x), bfhi(pc.y), bfhi(pc.z), bfhi(pc.w));
    float4 acc = make_float4(0.f, 0.f, 0.f, 0.f);

    int k0 = rowptr[c], k1 = rowptr[c + 1];
    if (k0 < k1) {
        int k = k0 + q;
        bool v = k < k1;
        int r = srcidx[v ? k : (k1 - 1)];
        uint4 pr = P4[(size_t)r * 16 + j];
        if (!v) pr = make_uint4(0u, 0u, 0u, 0u);

        for (int kb = k0; kb < k1; kb += 4) {
            uint4 pn = make_uint4(0u, 0u, 0u, 0u);
            if (kb + 4 < k1) {
                int k2 = kb + 4 + q;
                bool v2 = k2 < k1;
                int r2 = srcidx[v2 ? k2 : (k1 - 1)];
                uint4 t = P4[(size_t)r2 * 16 + j];
                if (v2) pn = t;
            }
            float4 h3r = make_float4(bflo(pr.x), bflo(pr.y), bflo(pr.z), bflo(pr.w));
            float4 h4r = make_float4(bfhi(pr.x), bfhi(pr.y), bfhi(pr.z), bfhi(pr.w));
            float d = h3r.x * h4c.x + h3r.y * h4c.y + h3r.z * h4c.z + h3r.w * h4c.w;
            d += __shfl_xor(d, 1, 64);
            d += __shfl_xor(d, 2, 64);
            d += __shfl_xor(d, 4, 64);
            d += __shfl_xor(d, 8, 64);
            float s = 1.0f / (1.0f + __expf(d));   // sigmoid(-d)
            float t = 1.0f - s;
            acc.x += s * h3r.x - t * h4r.x;
            acc.y += s * h3r.y - t * h4r.y;
            acc.z += s * h3r.z - t * h4r.z;
            acc.w += s * h3r.w - t * h4r.w;
            pr = pn;
        }
    }
    acc.x += __shfl_xor(acc.x, 16, 64);
    acc.y += __shfl_xor(acc.y, 16, 64);
    acc.z += __shfl_xor(acc.z, 16, 64);
    acc.w += __shfl_xor(acc.w, 16, 64);
    acc.x += __shfl_xor(acc.x, 32, 64);
    acc.y += __shfl_xor(acc.y, 32, 64);
    acc.z += __shfl_xor(acc.z, 32, 64);
    acc.w += __shfl_xor(acc.w, 32, 64);

    float4 hl = *(const float4*)&hloop[(size_t)c * H + j * 4];
    acc.x += hl.x; acc.y += hl.y; acc.z += hl.z; acc.w += hl.w;

    float ss = acc.x * acc.x + acc.y * acc.y + acc.z * acc.z + acc.w * acc.w;
    ss += __shfl_xor(ss, 1, 64);
    ss += __shfl_xor(ss, 2, 64);
    ss += __shfl_xor(ss, 4, 64);
    ss += __shfl_xor(ss, 8, 64);
    float inv = 1.0f / fmaxf(sqrtf(ss), 1e-12f);
    if (lane < 16) {
        float4 o;
        o.x = acc.x * inv; o.y = acc.y * inv; o.z = acc.z * inv; o.w = acc.w * inv;
        *(float4*)&Q[(size_t)c * H + j * 4] = o;
    }
}

// ---------- logits = Q@W_out^T + b_out ; out = log_softmax ----------
__global__ __launch_bounds__(256) void k_out(
    const float* __restrict__ Q, const float* __restrict__ W_out,
    const float* __restrict__ b_out, float* __restrict__ out, int n) {
    __shared__ float Wt[H][COUT];
    __shared__ float qrow[4][H];
    int tid = threadIdx.x;
    for (int idx = tid; idx < H * COUT; idx += 256) {
        int k = idx / COUT, c = idx % COUT;
        Wt[k][c] = W_out[c * H + k];
    }
    __syncthreads();
    int lane = tid & 63;
    int w = tid >> 6;
    float bb = (lane < COUT) ? b_out[lane] : 0.f;
    int wid = blockIdx.x * 4 + w;
    int nw = gridDim.x * 4;
    for (int r = wid; r < n; r += nw) {
        float q = Q[(size_t)r * H + lane];
        qrow[w][lane] = q;
        float logit = -3.0e38f;
        if (lane < COUT) {
            float a = bb;
#pragma unroll 8
            for (int k = 0; k < H; ++k) a += qrow[w][k] * Wt[k][lane];
            logit = a;
        }
        float m = logit;
#pragma unroll
        for (int off = 32; off; off >>= 1) m = fmaxf(m, __shfl_xor(m, off, 64));
        float ex = (lane < COUT) ? __expf(logit - m) : 0.f;
#pragma unroll
        for (int off = 32; off; off >>= 1) ex += __shfl_xor(ex, off, 64);
        if (lane < COUT) out[(size_t)r * COUT + lane] = (logit - m) - logf(ex);
    }
}

extern "C" void kernel_launch(void* const* d_in, const int* in_sizes, int n_in,
                              void* d_out, int out_size, void* d_ws, size_t ws_size,
                              hipStream_t stream) {
    const float* x     = (const float*)d_in[0];
    const int*   ei    = (const int*)d_in[1];
    const float* W_in  = (const float*)d_in[2];
    const float* b_in  = (const float*)d_in[3];
    const float* W1_0  = (const float*)d_in[4];
    const float* W2_0  = (const float*)d_in[5];
    const float* Wf_0  = (const float*)d_in[6];
    const float* W1_1  = (const float*)d_in[7];
    const float* W2_1  = (const float*)d_in[8];
    const float* Wf_1  = (const float*)d_in[9];
    const float* W_out = (const float*)d_in[10];
    const float* b_out = (const float*)d_in[11];
    float* out = (float*)d_out;

    int N = in_sizes[0] / FIN;
    int E = in_sizes[1] / 2;

    float* ws    = (float*)d_ws;
    uint4* Bp    = (uint4*)ws;                       // 4096 uint4 = 64KB
    float* Wct0  = ws + 16384;                       // 12288 floats
    float* Wct1  = Wct0 + 12288;                     // 12288
    float* Q     = Wct1 + 12288;                     // N*64
    unsigned* P  = (unsigned*)(Q + (size_t)N * H);   // N*64 u32
    float* hloop = (float*)(P + (size_t)N * H);      // N*64
    int* rowptr  = (int*)(hloop + (size_t)N * H);    // N+2
    int* deg     = rowptr + (N + 2);
    int* cursor  = deg + N;
    int* srcidx  = cursor + N;
    int* blocksum = srcidx + E;
    int* blockoff = blocksum + 256;

    k_pack_win<<<16, 256, 0, stream>>>(W_in, Bp);
    k_transpose_wc<<<(H * H + 255) / 256, 256, 0, stream>>>(W1_0, W2_0, Wf_0, Wct0);
    k_transpose_wc<<<(H * H + 255) / 256, 256, 0, stream>>>(W1_1, W2_1, Wf_1, Wct1);

    int nb = (N + 1023) / 1024;
    k_zero<<<(N + 255) / 256, 256, 0, stream>>>(deg, N);
    k_hist<<<(E + 255) / 256, 256, 0, stream>>>(ei, deg, E);
    k_scan1<<<nb, 256, 0, stream>>>(deg, rowptr, blocksum, N);
    k_scan2<<<1, 256, 0, stream>>>(blocksum, blockoff, nb);
    k_scan3<<<nb, 256, 0, stream>>>(rowptr, blockoff, cursor, N, E);
    k_scatter<<<(E + 255) / 256, 256, 0, stream>>>(ei, cursor, srcidx, E);

    int gm = (N + 63) / 64;
    k_in_gemm<<<gm, 256, 0, stream>>>(x, Bp, b_in, Q, N);

    for (int l = 0; l < 2; ++l) {
        const float* Wct = l ? Wct1 : Wct0;
        k_layer_gemm<<<gm, 256, 0, stream>>>(Q, Wct, P, hloop, N);
        k_agg<<<(N + 3) / 4, 256, 0, stream>>>(rowptr, srcidx, P, hloop, Q, N);
    }
    k_out<<<1024, 256, 0, stream>>>(Q, W_out, b_out, out, N);
}

// Round 5
// 423.744 us; speedup vs baseline: 2.1043x; 1.2674x over previous
//
#include <hip/hip_runtime.h>
#include <hip/hip_bf16.h>
#include <math.h>

#define H 64
#define FIN 512
#define COUT 40

typedef __attribute__((ext_vector_type(8))) short bf16x8;
typedef __attribute__((ext_vector_type(4))) float f32x4;

__device__ __forceinline__ unsigned short f2bf(float f) {
    union { float f; unsigned u; } v; v.f = f;
    unsigned r = v.u + 0x7FFF + ((v.u >> 16) & 1);   // RNE
    return (unsigned short)(r >> 16);
}
__device__ __forceinline__ float bflo(unsigned u) { return __uint_as_float(u << 16); }
__device__ __forceinline__ float bfhi(unsigned u) { return __uint_as_float(u & 0xffff0000u); }

// ---------- pack W_in into bf16 B-fragments: Bp[kb][n] = W_in[n][kb*8..+8] ----------
__global__ void k_pack_win(const float* __restrict__ W, uint4* __restrict__ Bp) {
    int t = blockIdx.x * blockDim.x + threadIdx.x;   // 4096 = 64 kb * 64 n
    if (t >= 64 * 64) return;
    int kb = t >> 6, n = t & 63;
    const float* src = &W[n * FIN + kb * 8];
    float4 a0 = *(const float4*)&src[0];
    float4 a1 = *(const float4*)&src[4];
    uint4 u;
    u.x = ((unsigned)f2bf(a0.y) << 16) | f2bf(a0.x);
    u.y = ((unsigned)f2bf(a0.w) << 16) | f2bf(a0.z);
    u.z = ((unsigned)f2bf(a1.y) << 16) | f2bf(a1.x);
    u.w = ((unsigned)f2bf(a1.w) << 16) | f2bf(a1.z);
    Bp[t] = u;
}

// ---------- pack layer weights: Bc[j][kb][n] = Wj[n][kb*8..+8], j in {W1,W2,Wf} ----------
__global__ void k_pack_wc(const float* __restrict__ W1, const float* __restrict__ W2,
                          const float* __restrict__ Wf, uint4* __restrict__ Bc) {
    int t = blockIdx.x * blockDim.x + threadIdx.x;   // 1536 = 3 * 8 kb * 64 n
    if (t >= 3 * 8 * 64) return;
    int j = t >> 9, kb = (t >> 6) & 7, n = t & 63;
    const float* W = (j == 0) ? W1 : (j == 1) ? W2 : Wf;
    const float* src = &W[n * H + kb * 8];
    float4 a0 = *(const float4*)&src[0];
    float4 a1 = *(const float4*)&src[4];
    uint4 u;
    u.x = ((unsigned)f2bf(a0.y) << 16) | f2bf(a0.x);
    u.y = ((unsigned)f2bf(a0.w) << 16) | f2bf(a0.z);
    u.z = ((unsigned)f2bf(a1.y) << 16) | f2bf(a1.x);
    u.w = ((unsigned)f2bf(a1.w) << 16) | f2bf(a1.z);
    Bc[t] = u;
}

// ---------- CSR build ----------
__global__ void k_zero(int* __restrict__ p, int n) {
    int i = blockIdx.x * blockDim.x + threadIdx.x;
    if (i < n) p[i] = 0;
}

__global__ void k_hist(const int* __restrict__ ei, int* __restrict__ deg, int nE) {
    int e = blockIdx.x * blockDim.x + threadIdx.x;
    if (e < nE) atomicAdd(&deg[ei[nE + e]], 1);
}

__global__ __launch_bounds__(256) void k_scan1(const int* __restrict__ deg, int* __restrict__ epos,
                                               int* __restrict__ blocksum, int n) {
    __shared__ int tmp[256];
    int t = threadIdx.x;
    int base = blockIdx.x * 1024 + t * 4;
    int v[4]; int s = 0;
#pragma unroll
    for (int i = 0; i < 4; ++i) { v[i] = (base + i < n) ? deg[base + i] : 0; s += v[i]; }
    tmp[t] = s;
    __syncthreads();
    int incl = s;
    for (int off = 1; off < 256; off <<= 1) {
        int y = (t >= off) ? tmp[t - off] : 0;
        __syncthreads();
        incl += y;
        tmp[t] = incl;
        __syncthreads();
    }
    if (t == 255) blocksum[blockIdx.x] = incl;
    int run = incl - s;
#pragma unroll
    for (int i = 0; i < 4; ++i) { if (base + i < n) epos[base + i] = run; run += v[i]; }
}

__global__ __launch_bounds__(256) void k_scan2(const int* __restrict__ blocksum,
                                               int* __restrict__ blockoff, int nb) {
    __shared__ int tmp[256];
    int t = threadIdx.x;
    int s = (t < nb) ? blocksum[t] : 0;
    tmp[t] = s;
    __syncthreads();
    int incl = s;
    for (int off = 1; off < 256; off <<= 1) {
        int y = (t >= off) ? tmp[t - off] : 0;
        __syncthreads();
        incl += y;
        tmp[t] = incl;
        __syncthreads();
    }
    if (t < nb) blockoff[t] = incl - s;
}

__global__ __launch_bounds__(256) void k_scan3(int* __restrict__ epos, const int* __restrict__ blockoff,
                                               int* __restrict__ cursor, int n, int nE) {
    int b = blockIdx.x;
    int off = blockoff[b];
    int base = b * 1024 + threadIdx.x * 4;
#pragma unroll
    for (int i = 0; i < 4; ++i) {
        if (base + i < n) {
            int p = epos[base + i] + off;
            epos[base + i] = p;
            cursor[base + i] = p;
        }
    }
    if (b == 0 && threadIdx.x == 0) epos[n] = nE;
}

__global__ void k_scatter(const int* __restrict__ ei, int* __restrict__ cursor,
                          int* __restrict__ srcidx, int nE) {
    int e = blockIdx.x * blockDim.x + threadIdx.x;
    if (e < nE) {
        int c = ei[nE + e];
        int p = atomicAdd(&cursor[c], 1);
        srcidx[p] = ei[e];
    }
}

// ---------- Q(bf16) = x @ W_in^T + b_in  (bf16 MFMA, fp32 accumulate) ----------
__global__ __launch_bounds__(256) void k_in_gemm(
    const float* __restrict__ x, const uint4* __restrict__ Bp,
    const float* __restrict__ bias, unsigned short* __restrict__ qbf, int n) {
    __shared__ uint4 As4[256];   // 64 rows x 32 k bf16, granule-swizzled
    __shared__ uint4 Bs4[256];   // [kg 0..3][col 0..63]
    int tid = threadIdx.x;
    int base = blockIdx.x * 64;
    int lane = tid & 63, w = tid >> 6;

    int srow = tid >> 2;
    int sg = tid & 3;
    int sgs = sg ^ ((srow >> 1) & 3);
    bool rowok = (base + srow) < n;
    const float* xsrc = &x[(size_t)(base + srow) * FIN + sg * 8];

    int arow = 16 * w + (lane & 15);
    int ag = (lane >> 4) ^ ((arow >> 1) & 3);
    int aidx = arow * 4 + ag;
    int kg = lane >> 4;

    f32x4 acc[4];
#pragma unroll
    for (int i = 0; i < 4; ++i) acc[i] = (f32x4){0.f, 0.f, 0.f, 0.f};

    for (int kk = 0; kk < FIN; kk += 32) {
        float4 a0 = make_float4(0.f, 0.f, 0.f, 0.f), a1 = a0;
        if (rowok) {
            a0 = *(const float4*)&xsrc[kk];
            a1 = *(const float4*)&xsrc[kk + 4];
        }
        uint4 bstage = Bp[((kk >> 3) + (tid >> 6)) * 64 + (tid & 63)];
        __syncthreads();
        {
            uint4 u;
            u.x = ((unsigned)f2bf(a0.y) << 16) | f2bf(a0.x);
            u.y = ((unsigned)f2bf(a0.w) << 16) | f2bf(a0.z);
            u.z = ((unsigned)f2bf(a1.y) << 16) | f2bf(a1.x);
            u.w = ((unsigned)f2bf(a1.w) << 16) | f2bf(a1.z);
            As4[srow * 4 + sgs] = u;
            Bs4[tid] = bstage;
        }
        __syncthreads();
        bf16x8 af = *(const bf16x8*)&As4[aidx];
#pragma unroll
        for (int nt = 0; nt < 4; ++nt) {
            bf16x8 bfr = *(const bf16x8*)&Bs4[kg * 64 + nt * 16 + (lane & 15)];
            acc[nt] = __builtin_amdgcn_mfma_f32_16x16x32_bf16(af, bfr, acc[nt], 0, 0, 0);
        }
    }
    int col0 = lane & 15, rowg = lane >> 4;
#pragma unroll
    for (int nt = 0; nt < 4; ++nt) {
        float bv = bias[nt * 16 + col0];
#pragma unroll
        for (int reg = 0; reg < 4; ++reg) {
            int r = base + 16 * w + rowg * 4 + reg;
            if (r < n) qbf[(size_t)r * H + nt * 16 + col0] = f2bf(acc[nt][reg] + bv);
        }
    }
}

// ---------- P = pack(bf16(Q@W1^T), bf16(Q@W2^T)), hl = bf16(relu(Q@Wf^T)) ----------
// bf16 MFMA; Q is bf16 [n][64]; Bc = packed fragments [3][8][64]
__global__ __launch_bounds__(256) void k_layer_gemm(
    const uint4* __restrict__ Qbf, const uint4* __restrict__ Bc,
    unsigned* __restrict__ P, unsigned short* __restrict__ hl, int n) {
    __shared__ uint4 Qs[512];   // 64 rows x 8 granules, XOR-swizzled
    int tid = threadIdx.x;
    int base = blockIdx.x * 64;
    int lane = tid & 63, w = tid >> 6;
    {
        int r = tid >> 2, g0 = (tid & 3) * 2;
        uint4 u0 = make_uint4(0u, 0u, 0u, 0u), u1 = u0;
        if (base + r < n) {
            u0 = Qbf[(size_t)(base + r) * 8 + g0];
            u1 = Qbf[(size_t)(base + r) * 8 + g0 + 1];
        }
        Qs[r * 8 + (g0 ^ (r & 7))] = u0;
        Qs[r * 8 + ((g0 + 1) ^ (r & 7))] = u1;
    }
    __syncthreads();

    int arow = w * 16 + (lane & 15);
    f32x4 acc[12];
#pragma unroll
    for (int i = 0; i < 12; ++i) acc[i] = (f32x4){0.f, 0.f, 0.f, 0.f};

#pragma unroll
    for (int ks = 0; ks < 2; ++ks) {
        int g = ks * 4 + (lane >> 4);           // granule == global kb
        bf16x8 af = *(const bf16x8*)&Qs[arow * 8 + (g ^ (arow & 7))];
#pragma unroll
        for (int j = 0; j < 3; ++j) {
#pragma unroll
            for (int nt = 0; nt < 4; ++nt) {
                bf16x8 bfr = *(const bf16x8*)&Bc[(j * 8 + g) * 64 + nt * 16 + (lane & 15)];
                acc[j * 4 + nt] = __builtin_amdgcn_mfma_f32_16x16x32_bf16(af, bfr, acc[j * 4 + nt], 0, 0, 0);
            }
        }
    }
    int col0 = lane & 15, rowg = lane >> 4;
#pragma unroll
    for (int nt = 0; nt < 4; ++nt) {
#pragma unroll
        for (int reg = 0; reg < 4; ++reg) {
            int r = base + w * 16 + rowg * 4 + reg;
            if (r < n) {
                int col = nt * 16 + col0;
                unsigned pv = ((unsigned)f2bf(acc[4 + nt][reg]) << 16) | f2bf(acc[nt][reg]);
                P[(size_t)r * H + col] = pv;
                hl[(size_t)r * H + col] = f2bf(fmaxf(acc[8 + nt][reg], 0.f));
            }
        }
    }
}

// ---------- CSR gather aggregation (packed bf16), 4 edges/wave ----------
// LAYER 0: write normalized Q (bf16). LAYER 1: fused logits + log_softmax -> out.
template <int LAYER>
__global__ __launch_bounds__(256) void k_agg(
    const int* __restrict__ rowptr, const int* __restrict__ srcidx,
    const unsigned* __restrict__ P, const unsigned* __restrict__ hl32,
    unsigned* __restrict__ Qbf32,
    const float* __restrict__ W_out, const float* __restrict__ b_out,
    float* __restrict__ out, int n) {
    __shared__ float Wt[H][COUT];   // [k][c], used in LAYER 1
    __shared__ float qrow[4][H];
    int tid = threadIdx.x;
    int lane = tid & 63;
    int w = tid >> 6;
    if (LAYER == 1) {
        for (int idx = tid; idx < H * COUT; idx += 256) {
            int c = idx >> 6, k = idx & 63;
            Wt[k][c] = W_out[idx];
        }
        __syncthreads();
    }
    int c = blockIdx.x * 4 + w;
    if (c >= n) return;
    int q = lane >> 4;
    int j = lane & 15;
    const uint4* P4 = (const uint4*)P;

    uint4 pc = P4[(size_t)c * 16 + j];
    float4 h4c = make_float4(bfhi(pc.x), bfhi(pc.y), bfhi(pc.z), bfhi(pc.w));
    float4 acc = make_float4(0.f, 0.f, 0.f, 0.f);

    int k0 = rowptr[c], k1 = rowptr[c + 1];
    if (k0 < k1) {
        int k = k0 + q;
        bool v = k < k1;
        int r = srcidx[v ? k : (k1 - 1)];
        uint4 pr = P4[(size_t)r * 16 + j];
        if (!v) pr = make_uint4(0u, 0u, 0u, 0u);

        for (int kb = k0; kb < k1; kb += 4) {
            uint4 pn = make_uint4(0u, 0u, 0u, 0u);
            if (kb + 4 < k1) {
                int k2 = kb + 4 + q;
                bool v2 = k2 < k1;
                int r2 = srcidx[v2 ? k2 : (k1 - 1)];
                uint4 tt = P4[(size_t)r2 * 16 + j];
                if (v2) pn = tt;
            }
            float4 h3r = make_float4(bflo(pr.x), bflo(pr.y), bflo(pr.z), bflo(pr.w));
            float4 h4r = make_float4(bfhi(pr.x), bfhi(pr.y), bfhi(pr.z), bfhi(pr.w));
            float d = h3r.x * h4c.x + h3r.y * h4c.y + h3r.z * h4c.z + h3r.w * h4c.w;
            d += __shfl_xor(d, 1, 64);
            d += __shfl_xor(d, 2, 64);
            d += __shfl_xor(d, 4, 64);
            d += __shfl_xor(d, 8, 64);
            float s = 1.0f / (1.0f + __expf(d));   // sigmoid(-d)
            float t = 1.0f - s;
            acc.x += s * h3r.x - t * h4r.x;
            acc.y += s * h3r.y - t * h4r.y;
            acc.z += s * h3r.z - t * h4r.z;
            acc.w += s * h3r.w - t * h4r.w;
            pr = pn;
        }
    }
    acc.x += __shfl_xor(acc.x, 16, 64);
    acc.y += __shfl_xor(acc.y, 16, 64);
    acc.z += __shfl_xor(acc.z, 16, 64);
    acc.w += __shfl_xor(acc.w, 16, 64);
    acc.x += __shfl_xor(acc.x, 32, 64);
    acc.y += __shfl_xor(acc.y, 32, 64);
    acc.z += __shfl_xor(acc.z, 32, 64);
    acc.w += __shfl_xor(acc.w, 32, 64);

    uint2 hv = *(const uint2*)&hl32[(size_t)c * 32 + j * 2];
    acc.x += bflo(hv.x); acc.y += bfhi(hv.x);
    acc.z += bflo(hv.y); acc.w += bfhi(hv.y);

    float ss = acc.x * acc.x + acc.y * acc.y + acc.z * acc.z + acc.w * acc.w;
    ss += __shfl_xor(ss, 1, 64);
    ss += __shfl_xor(ss, 2, 64);
    ss += __shfl_xor(ss, 4, 64);
    ss += __shfl_xor(ss, 8, 64);
    float inv = 1.0f / fmaxf(sqrtf(ss), 1e-12f);

    if (LAYER == 0) {
        if (lane < 16) {
            uint2 o;
            o.x = ((unsigned)f2bf(acc.y * inv) << 16) | f2bf(acc.x * inv);
            o.y = ((unsigned)f2bf(acc.w * inv) << 16) | f2bf(acc.z * inv);
            *(uint2*)&Qbf32[(size_t)c * 32 + j * 2] = o;
        }
    } else {
        if (lane < 16) {
            float4 o;
            o.x = acc.x * inv; o.y = acc.y * inv; o.z = acc.z * inv; o.w = acc.w * inv;
            *(float4*)&qrow[w][j * 4] = o;
        }
        float logit = -3.0e38f;
        if (lane < COUT) {
            float a = b_out[lane];
#pragma unroll 8
            for (int k = 0; k < H; ++k) a += qrow[w][k] * Wt[k][lane];
            logit = a;
        }
        float m = logit;
#pragma unroll
        for (int off = 32; off; off >>= 1) m = fmaxf(m, __shfl_xor(m, off, 64));
        float ex = (lane < COUT) ? __expf(logit - m) : 0.f;
#pragma unroll
        for (int off = 32; off; off >>= 1) ex += __shfl_xor(ex, off, 64);
        if (lane < COUT) out[(size_t)c * COUT + lane] = (logit - m) - logf(ex);
    }
}

extern "C" void kernel_launch(void* const* d_in, const int* in_sizes, int n_in,
                              void* d_out, int out_size, void* d_ws, size_t ws_size,
                              hipStream_t stream) {
    const float* x     = (const float*)d_in[0];
    const int*   ei    = (const int*)d_in[1];
    const float* W_in  = (const float*)d_in[2];
    const float* b_in  = (const float*)d_in[3];
    const float* W1_0  = (const float*)d_in[4];
    const float* W2_0  = (const float*)d_in[5];
    const float* Wf_0  = (const float*)d_in[6];
    const float* W1_1  = (const float*)d_in[7];
    const float* W2_1  = (const float*)d_in[8];
    const float* Wf_1  = (const float*)d_in[9];
    const float* W_out = (const float*)d_in[10];
    const float* b_out = (const float*)d_in[11];
    float* out = (float*)d_out;

    int N = in_sizes[0] / FIN;
    int E = in_sizes[1] / 2;

    uint4* Bp    = (uint4*)d_ws;                     // 4096 uint4
    uint4* Bc0   = Bp + 4096;                        // 1536
    uint4* Bc1   = Bc0 + 1536;                       // 1536
    unsigned* Qbf32 = (unsigned*)(Bc1 + 1536);       // N*32 u32 (bf16 Q)
    unsigned* P  = Qbf32 + (size_t)N * 32;           // N*64 u32 (packed h3|h4)
    unsigned* hl32 = P + (size_t)N * H;              // N*32 u32 (bf16 hloop)
    int* rowptr  = (int*)(hl32 + (size_t)N * 32);    // N+2
    int* deg     = rowptr + (N + 2);
    int* cursor  = deg + N;
    int* srcidx  = cursor + N;
    int* blocksum = srcidx + E;
    int* blockoff = blocksum + 256;

    k_pack_win<<<16, 256, 0, stream>>>(W_in, Bp);
    k_pack_wc<<<6, 256, 0, stream>>>(W1_0, W2_0, Wf_0, Bc0);
    k_pack_wc<<<6, 256, 0, stream>>>(W1_1, W2_1, Wf_1, Bc1);

    int nb = (N + 1023) / 1024;
    k_zero<<<(N + 255) / 256, 256, 0, stream>>>(deg, N);
    k_hist<<<(E + 255) / 256, 256, 0, stream>>>(ei, deg, E);
    k_scan1<<<nb, 256, 0, stream>>>(deg, rowptr, blocksum, N);
    k_scan2<<<1, 256, 0, stream>>>(blocksum, blockoff, nb);
    k_scan3<<<nb, 256, 0, stream>>>(rowptr, blockoff, cursor, N, E);
    k_scatter<<<(E + 255) / 256, 256, 0, stream>>>(ei, cursor, srcidx, E);

    int gm = (N + 63) / 64;
    k_in_gemm<<<gm, 256, 0, stream>>>(x, Bp, b_in, (unsigned short*)Qbf32, N);

    int ga = (N + 3) / 4;
    // layer 0
    k_layer_gemm<<<gm, 256, 0, stream>>>((const uint4*)Qbf32, Bc0, P, (unsigned short*)hl32, N);
    k_agg<0><<<ga, 256, 0, stream>>>(rowptr, srcidx, P, hl32, Qbf32, W_out, b_out, out, N);
    // layer 1 (fused output head)
    k_layer_gemm<<<gm, 256, 0, stream>>>((const uint4*)Qbf32, Bc1, P, (unsigned short*)hl32, N);
    k_agg<1><<<ga, 256, 0, stream>>>(rowptr, srcidx, P, hl32, Qbf32, W_out, b_out, out, N);
}

// Round 6
// 407.366 us; speedup vs baseline: 2.1889x; 1.0402x over previous
//
#include <hip/hip_runtime.h>
#include <hip/hip_bf16.h>
#include <math.h>

#define H 64
#define FIN 512
#define COUT 40

typedef __attribute__((ext_vector_type(8))) short bf16x8;
typedef __attribute__((ext_vector_type(4))) float f32x4;

__device__ __forceinline__ unsigned short f2bf(float f) {
    union { float f; unsigned u; } v; v.f = f;
    unsigned r = v.u + 0x7FFF + ((v.u >> 16) & 1);   // RNE
    return (unsigned short)(r >> 16);
}
__device__ __forceinline__ float bflo(unsigned u) { return __uint_as_float(u << 16); }
__device__ __forceinline__ float bfhi(unsigned u) { return __uint_as_float(u & 0xffff0000u); }

// ---------- unified weight pack: Bp[kb][n] (W_in) + Bc0/Bc1 [j][kb][n] ----------
__global__ void k_pack(const float* __restrict__ W_in,
                       const float* __restrict__ W1_0, const float* __restrict__ W2_0,
                       const float* __restrict__ Wf_0,
                       const float* __restrict__ W1_1, const float* __restrict__ W2_1,
                       const float* __restrict__ Wf_1,
                       uint4* __restrict__ Bp, uint4* __restrict__ Bc0, uint4* __restrict__ Bc1) {
    int t = blockIdx.x * blockDim.x + threadIdx.x;
    const float* src;
    uint4* dst;
    if (t < 4096) {                       // W_in: 64 kb x 64 n
        int kb = t >> 6, n = t & 63;
        src = &W_in[n * FIN + kb * 8];
        dst = &Bp[t];
    } else if (t < 4096 + 1536) {         // layer 0
        int u = t - 4096;
        int j = u >> 9, kb = (u >> 6) & 7, n = u & 63;
        const float* W = (j == 0) ? W1_0 : (j == 1) ? W2_0 : Wf_0;
        src = &W[n * H + kb * 8];
        dst = &Bc0[u];
    } else if (t < 4096 + 3072) {         // layer 1
        int u = t - 4096 - 1536;
        int j = u >> 9, kb = (u >> 6) & 7, n = u & 63;
        const float* W = (j == 0) ? W1_1 : (j == 1) ? W2_1 : Wf_1;
        src = &W[n * H + kb * 8];
        dst = &Bc1[u];
    } else return;
    float4 a0 = *(const float4*)&src[0];
    float4 a1 = *(const float4*)&src[4];
    uint4 u;
    u.x = ((unsigned)f2bf(a0.y) << 16) | f2bf(a0.x);
    u.y = ((unsigned)f2bf(a0.w) << 16) | f2bf(a0.z);
    u.z = ((unsigned)f2bf(a1.y) << 16) | f2bf(a1.x);
    u.w = ((unsigned)f2bf(a1.w) << 16) | f2bf(a1.z);
    *dst = u;
}

// ---------- CSR build ----------
__global__ void k_zero(int* __restrict__ p, int n) {
    int i = blockIdx.x * blockDim.x + threadIdx.x;
    if (i < n) p[i] = 0;
}

__global__ void k_hist(const int* __restrict__ ei, int* __restrict__ deg, int nE) {
    int e = blockIdx.x * blockDim.x + threadIdx.x;
    if (e < nE) atomicAdd(&deg[ei[nE + e]], 1);
}

__global__ __launch_bounds__(256) void k_scan1(const int* __restrict__ deg, int* __restrict__ epos,
                                               int* __restrict__ blocksum, int n) {
    __shared__ int tmp[256];
    int t = threadIdx.x;
    int base = blockIdx.x * 1024 + t * 4;
    int v[4]; int s = 0;
#pragma unroll
    for (int i = 0; i < 4; ++i) { v[i] = (base + i < n) ? deg[base + i] : 0; s += v[i]; }
    tmp[t] = s;
    __syncthreads();
    int incl = s;
    for (int off = 1; off < 256; off <<= 1) {
        int y = (t >= off) ? tmp[t - off] : 0;
        __syncthreads();
        incl += y;
        tmp[t] = incl;
        __syncthreads();
    }
    if (t == 255) blocksum[blockIdx.x] = incl;
    int run = incl - s;
#pragma unroll
    for (int i = 0; i < 4; ++i) { if (base + i < n) epos[base + i] = run; run += v[i]; }
}

__global__ __launch_bounds__(256) void k_scan2(const int* __restrict__ blocksum,
                                               int* __restrict__ blockoff, int nb) {
    __shared__ int tmp[256];
    int t = threadIdx.x;
    int s = (t < nb) ? blocksum[t] : 0;
    tmp[t] = s;
    __syncthreads();
    int incl = s;
    for (int off = 1; off < 256; off <<= 1) {
        int y = (t >= off) ? tmp[t - off] : 0;
        __syncthreads();
        incl += y;
        tmp[t] = incl;
        __syncthreads();
    }
    if (t < nb) blockoff[t] = incl - s;
}

__global__ __launch_bounds__(256) void k_scan3(int* __restrict__ epos, const int* __restrict__ blockoff,
                                               int* __restrict__ cursor, int n, int nE) {
    int b = blockIdx.x;
    int off = blockoff[b];
    int base = b * 1024 + threadIdx.x * 4;
#pragma unroll
    for (int i = 0; i < 4; ++i) {
        if (base + i < n) {
            int p = epos[base + i] + off;
            epos[base + i] = p;
            cursor[base + i] = p;
        }
    }
    if (b == 0 && threadIdx.x == 0) epos[n] = nE;
}

__global__ void k_scatter(const int* __restrict__ ei, int* __restrict__ cursor,
                          int* __restrict__ srcidx, int nE) {
    int e = blockIdx.x * blockDim.x + threadIdx.x;
    if (e < nE) {
        int c = ei[nE + e];
        int p = atomicAdd(&cursor[c], 1);
        srcidx[p] = ei[e];
    }
}

// ---------- Q(bf16) = x @ W_in^T + b_in  (bf16 MFMA, fp32 accumulate) ----------
__global__ __launch_bounds__(256) void k_in_gemm(
    const float* __restrict__ x, const uint4* __restrict__ Bp,
    const float* __restrict__ bias, unsigned short* __restrict__ qbf, int n) {
    __shared__ uint4 As4[256];
    __shared__ uint4 Bs4[256];
    int tid = threadIdx.x;
    int base = blockIdx.x * 64;
    int lane = tid & 63, w = tid >> 6;

    int srow = tid >> 2;
    int sg = tid & 3;
    int sgs = sg ^ ((srow >> 1) & 3);
    bool rowok = (base + srow) < n;
    const float* xsrc = &x[(size_t)(base + srow) * FIN + sg * 8];

    int arow = 16 * w + (lane & 15);
    int ag = (lane >> 4) ^ ((arow >> 1) & 3);
    int aidx = arow * 4 + ag;
    int kg = lane >> 4;

    f32x4 acc[4];
#pragma unroll
    for (int i = 0; i < 4; ++i) acc[i] = (f32x4){0.f, 0.f, 0.f, 0.f};

    for (int kk = 0; kk < FIN; kk += 32) {
        float4 a0 = make_float4(0.f, 0.f, 0.f, 0.f), a1 = a0;
        if (rowok) {
            a0 = *(const float4*)&xsrc[kk];
            a1 = *(const float4*)&xsrc[kk + 4];
        }
        uint4 bstage = Bp[((kk >> 3) + (tid >> 6)) * 64 + (tid & 63)];
        __syncthreads();
        {
            uint4 u;
            u.x = ((unsigned)f2bf(a0.y) << 16) | f2bf(a0.x);
            u.y = ((unsigned)f2bf(a0.w) << 16) | f2bf(a0.z);
            u.z = ((unsigned)f2bf(a1.y) << 16) | f2bf(a1.x);
            u.w = ((unsigned)f2bf(a1.w) << 16) | f2bf(a1.z);
            As4[srow * 4 + sgs] = u;
            Bs4[tid] = bstage;
        }
        __syncthreads();
        bf16x8 af = *(const bf16x8*)&As4[aidx];
#pragma unroll
        for (int nt = 0; nt < 4; ++nt) {
            bf16x8 bfr = *(const bf16x8*)&Bs4[kg * 64 + nt * 16 + (lane & 15)];
            acc[nt] = __builtin_amdgcn_mfma_f32_16x16x32_bf16(af, bfr, acc[nt], 0, 0, 0);
        }
    }
    int col0 = lane & 15, rowg = lane >> 4;
#pragma unroll
    for (int nt = 0; nt < 4; ++nt) {
        float bv = bias[nt * 16 + col0];
#pragma unroll
        for (int reg = 0; reg < 4; ++reg) {
            int r = base + 16 * w + rowg * 4 + reg;
            if (r < n) qbf[(size_t)r * H + nt * 16 + col0] = f2bf(acc[nt][reg] + bv);
        }
    }
}

// ---------- P = pack(bf16(Q@W1^T), bf16(Q@W2^T)), hl = bf16(relu(Q@Wf^T)) ----------
__global__ __launch_bounds__(256) void k_layer_gemm(
    const uint4* __restrict__ Qbf, const uint4* __restrict__ Bc,
    unsigned* __restrict__ P, unsigned short* __restrict__ hl, int n) {
    __shared__ uint4 Qs[512];
    int tid = threadIdx.x;
    int base = blockIdx.x * 64;
    int lane = tid & 63, w = tid >> 6;
    {
        int r = tid >> 2, g0 = (tid & 3) * 2;
        uint4 u0 = make_uint4(0u, 0u, 0u, 0u), u1 = u0;
        if (base + r < n) {
            u0 = Qbf[(size_t)(base + r) * 8 + g0];
            u1 = Qbf[(size_t)(base + r) * 8 + g0 + 1];
        }
        Qs[r * 8 + (g0 ^ (r & 7))] = u0;
        Qs[r * 8 + ((g0 + 1) ^ (r & 7))] = u1;
    }
    __syncthreads();

    int arow = w * 16 + (lane & 15);
    f32x4 acc[12];
#pragma unroll
    for (int i = 0; i < 12; ++i) acc[i] = (f32x4){0.f, 0.f, 0.f, 0.f};

#pragma unroll
    for (int ks = 0; ks < 2; ++ks) {
        int g = ks * 4 + (lane >> 4);
        bf16x8 af = *(const bf16x8*)&Qs[arow * 8 + (g ^ (arow & 7))];
#pragma unroll
        for (int j = 0; j < 3; ++j) {
#pragma unroll
            for (int nt = 0; nt < 4; ++nt) {
                bf16x8 bfr = *(const bf16x8*)&Bc[(j * 8 + g) * 64 + nt * 16 + (lane & 15)];
                acc[j * 4 + nt] = __builtin_amdgcn_mfma_f32_16x16x32_bf16(af, bfr, acc[j * 4 + nt], 0, 0, 0);
            }
        }
    }
    int col0 = lane & 15, rowg = lane >> 4;
#pragma unroll
    for (int nt = 0; nt < 4; ++nt) {
#pragma unroll
        for (int reg = 0; reg < 4; ++reg) {
            int r = base + w * 16 + rowg * 4 + reg;
            if (r < n) {
                int col = nt * 16 + col0;
                unsigned pv = ((unsigned)f2bf(acc[4 + nt][reg]) << 16) | f2bf(acc[nt][reg]);
                P[(size_t)r * H + col] = pv;
                hl[(size_t)r * H + col] = f2bf(fmaxf(acc[8 + nt][reg], 0.f));
            }
        }
    }
}

// ---------- CSR gather aggregation, 8 edges/iteration (2 per quarter), 2-in-flight ----------
template <int LAYER>
__global__ __launch_bounds__(256) void k_agg(
    const int* __restrict__ rowptr, const int* __restrict__ srcidx,
    const unsigned* __restrict__ P, const unsigned* __restrict__ hl32,
    unsigned* __restrict__ Qbf32,
    const float* __restrict__ W_out, const float* __restrict__ b_out,
    float* __restrict__ out, int n) {
    __shared__ float Wt[H][COUT + 1];   // +1 pad: bank stride 41%32=9, coprime -> conflict-free
    __shared__ float qrow[4][H];
    int tid = threadIdx.x;
    int lane = tid & 63;
    int w = tid >> 6;
    if (LAYER == 1) {
        for (int idx = tid; idx < H * COUT; idx += 256) {
            int c = idx >> 6, k = idx & 63;
            Wt[k][c] = W_out[idx];
        }
        __syncthreads();
    }
    int c = blockIdx.x * 4 + w;
    if (c >= n) return;
    int q = lane >> 4;
    int j = lane & 15;
    const uint4* P4 = (const uint4*)P;

    uint4 pc = P4[(size_t)c * 16 + j];
    float4 h4c = make_float4(bfhi(pc.x), bfhi(pc.y), bfhi(pc.z), bfhi(pc.w));
    float4 acc = make_float4(0.f, 0.f, 0.f, 0.f);

    int k0 = rowptr[c], k1 = rowptr[c + 1];
    if (k0 < k1) {
        const uint4 Z = make_uint4(0u, 0u, 0u, 0u);
        // prologue: gather batch A (slots 2q, 2q+1)
        int e0 = k0 + 2 * q;
        uint4 pA0 = Z, pA1 = Z;
        if (e0 < k1)     pA0 = P4[(size_t)srcidx[e0] * 16 + j];
        if (e0 + 1 < k1) pA1 = P4[(size_t)srcidx[e0 + 1] * 16 + j];

        for (int kb = k0; kb < k1; kb += 8) {
            // issue batch B gathers (2 independent loads in flight during compute)
            uint4 pB0 = Z, pB1 = Z;
            int f0 = kb + 8 + 2 * q;
            if (f0 < k1)     pB0 = P4[(size_t)srcidx[f0] * 16 + j];
            if (f0 + 1 < k1) pB1 = P4[(size_t)srcidx[f0 + 1] * 16 + j];

            // compute batch A (two edges, interleaved reduce chains)
            float4 h30 = make_float4(bflo(pA0.x), bflo(pA0.y), bflo(pA0.z), bflo(pA0.w));
            float4 h40 = make_float4(bfhi(pA0.x), bfhi(pA0.y), bfhi(pA0.z), bfhi(pA0.w));
            float4 h31 = make_float4(bflo(pA1.x), bflo(pA1.y), bflo(pA1.z), bflo(pA1.w));
            float4 h41 = make_float4(bfhi(pA1.x), bfhi(pA1.y), bfhi(pA1.z), bfhi(pA1.w));
            float d0 = h30.x * h4c.x + h30.y * h4c.y + h30.z * h4c.z + h30.w * h4c.w;
            float d1 = h31.x * h4c.x + h31.y * h4c.y + h31.z * h4c.z + h31.w * h4c.w;
            d0 += __shfl_xor(d0, 1, 64);  d1 += __shfl_xor(d1, 1, 64);
            d0 += __shfl_xor(d0, 2, 64);  d1 += __shfl_xor(d1, 2, 64);
            d0 += __shfl_xor(d0, 4, 64);  d1 += __shfl_xor(d1, 4, 64);
            d0 += __shfl_xor(d0, 8, 64);  d1 += __shfl_xor(d1, 8, 64);
            float s0 = 1.0f / (1.0f + __expf(d0));   // sigmoid(-d0)
            float s1 = 1.0f / (1.0f + __expf(d1));
            float t0 = 1.0f - s0, t1 = 1.0f - s1;
            acc.x += s0 * h30.x - t0 * h40.x + s1 * h31.x - t1 * h41.x;
            acc.y += s0 * h30.y - t0 * h40.y + s1 * h31.y - t1 * h41.y;
            acc.z += s0 * h30.z - t0 * h40.z + s1 * h31.z - t1 * h41.z;
            acc.w += s0 * h30.w - t0 * h40.w + s1 * h31.w - t1 * h41.w;
            pA0 = pB0; pA1 = pB1;
        }
    }
    // sum across the 4 quarters
    acc.x += __shfl_xor(acc.x, 16, 64);
    acc.y += __shfl_xor(acc.y, 16, 64);
    acc.z += __shfl_xor(acc.z, 16, 64);
    acc.w += __shfl_xor(acc.w, 16, 64);
    acc.x += __shfl_xor(acc.x, 32, 64);
    acc.y += __shfl_xor(acc.y, 32, 64);
    acc.z += __shfl_xor(acc.z, 32, 64);
    acc.w += __shfl_xor(acc.w, 32, 64);

    uint2 hv = *(const uint2*)&hl32[(size_t)c * 32 + j * 2];
    acc.x += bflo(hv.x); acc.y += bfhi(hv.x);
    acc.z += bflo(hv.y); acc.w += bfhi(hv.y);

    float ss = acc.x * acc.x + acc.y * acc.y + acc.z * acc.z + acc.w * acc.w;
    ss += __shfl_xor(ss, 1, 64);
    ss += __shfl_xor(ss, 2, 64);
    ss += __shfl_xor(ss, 4, 64);
    ss += __shfl_xor(ss, 8, 64);
    float inv = 1.0f / fmaxf(sqrtf(ss), 1e-12f);

    if (LAYER == 0) {
        if (lane < 16) {
            uint2 o;
            o.x = ((unsigned)f2bf(acc.y * inv) << 16) | f2bf(acc.x * inv);
            o.y = ((unsigned)f2bf(acc.w * inv) << 16) | f2bf(acc.z * inv);
            *(uint2*)&Qbf32[(size_t)c * 32 + j * 2] = o;
        }
    } else {
        if (lane < 16) {
            float4 o;
            o.x = acc.x * inv; o.y = acc.y * inv; o.z = acc.z * inv; o.w = acc.w * inv;
            *(float4*)&qrow[w][j * 4] = o;
        }
        float logit = -3.0e38f;
        if (lane < COUT) {
            float a = b_out[lane];
#pragma unroll 8
            for (int k = 0; k < H; ++k) a += qrow[w][k] * Wt[k][lane];
            logit = a;
        }
        float m = logit;
#pragma unroll
        for (int off = 32; off; off >>= 1) m = fmaxf(m, __shfl_xor(m, off, 64));
        float ex = (lane < COUT) ? __expf(logit - m) : 0.f;
#pragma unroll
        for (int off = 32; off; off >>= 1) ex += __shfl_xor(ex, off, 64);
        if (lane < COUT) out[(size_t)c * COUT + lane] = (logit - m) - logf(ex);
    }
}

extern "C" void kernel_launch(void* const* d_in, const int* in_sizes, int n_in,
                              void* d_out, int out_size, void* d_ws, size_t ws_size,
                              hipStream_t stream) {
    const float* x     = (const float*)d_in[0];
    const int*   ei    = (const int*)d_in[1];
    const float* W_in  = (const float*)d_in[2];
    const float* b_in  = (const float*)d_in[3];
    const float* W1_0  = (const float*)d_in[4];
    const float* W2_0  = (const float*)d_in[5];
    const float* Wf_0  = (const float*)d_in[6];
    const float* W1_1  = (const float*)d_in[7];
    const float* W2_1  = (const float*)d_in[8];
    const float* Wf_1  = (const float*)d_in[9];
    const float* W_out = (const float*)d_in[10];
    const float* b_out = (const float*)d_in[11];
    float* out = (float*)d_out;

    int N = in_sizes[0] / FIN;
    int E = in_sizes[1] / 2;

    uint4* Bp    = (uint4*)d_ws;                     // 4096 uint4
    uint4* Bc0   = Bp + 4096;                        // 1536
    uint4* Bc1   = Bc0 + 1536;                       // 1536
    unsigned* Qbf32 = (unsigned*)(Bc1 + 1536);       // N*32 u32 (bf16 Q)
    unsigned* P  = Qbf32 + (size_t)N * 32;           // N*64 u32 (packed h4|h3)
    unsigned* hl32 = P + (size_t)N * H;              // N*32 u32 (bf16 hloop)
    int* rowptr  = (int*)(hl32 + (size_t)N * 32);    // N+2
    int* deg     = rowptr + (N + 2);
    int* cursor  = deg + N;
    int* srcidx  = cursor + N;
    int* blocksum = srcidx + E;
    int* blockoff = blocksum + 256;

    k_pack<<<28, 256, 0, stream>>>(W_in, W1_0, W2_0, Wf_0, W1_1, W2_1, Wf_1, Bp, Bc0, Bc1);

    int nb = (N + 1023) / 1024;
    k_zero<<<(N + 255) / 256, 256, 0, stream>>>(deg, N);
    k_hist<<<(E + 255) / 256, 256, 0, stream>>>(ei, deg, E);
    k_scan1<<<nb, 256, 0, stream>>>(deg, rowptr, blocksum, N);
    k_scan2<<<1, 256, 0, stream>>>(blocksum, blockoff, nb);
    k_scan3<<<nb, 256, 0, stream>>>(rowptr, blockoff, cursor, N, E);
    k_scatter<<<(E + 255) / 256, 256, 0, stream>>>(ei, cursor, srcidx, E);

    int gm = (N + 63) / 64;
    k_in_gemm<<<gm, 256, 0, stream>>>(x, Bp, b_in, (unsigned short*)Qbf32, N);

    int ga = (N + 3) / 4;
    // layer 0
    k_layer_gemm<<<gm, 256, 0, stream>>>((const uint4*)Qbf32, Bc0, P, (unsigned short*)hl32, N);
    k_agg<0><<<ga, 256, 0, stream>>>(rowptr, srcidx, P, hl32, Qbf32, W_out, b_out, out, N);
    // layer 1 (fused output head)
    k_layer_gemm<<<gm, 256, 0, stream>>>((const uint4*)Qbf32, Bc1, P, (unsigned short*)hl32, N);
    k_agg<1><<<ga, 256, 0, stream>>>(rowptr, srcidx, P, hl32, Qbf32, W_out, b_out, out, N);
}

// Round 7
// 352.645 us; speedup vs baseline: 2.5286x; 1.1552x over previous
//
#include <hip/hip_runtime.h>
#include <hip/hip_bf16.h>
#include <math.h>

#define H 64
#define FIN 512
#define COUT 40

typedef __attribute__((ext_vector_type(8))) short bf16x8;
typedef __attribute__((ext_vector_type(4))) float f32x4;

__device__ __forceinline__ unsigned short f2bf(float f) {
    union { float f; unsigned u; } v; v.f = f;
    unsigned r = v.u + 0x7FFF + ((v.u >> 16) & 1);   // RNE
    return (unsigned short)(r >> 16);
}
__device__ __forceinline__ float bflo(unsigned u) { return __uint_as_float(u << 16); }
__device__ __forceinline__ float bfhi(unsigned u) { return __uint_as_float(u & 0xffff0000u); }

// ---------- unified weight pack: Bp (W_in), Bc0/Bc1 (layers), Bo (W_out, 48-col padded) ----------
__global__ void k_pack(const float* __restrict__ W_in,
                       const float* __restrict__ W1_0, const float* __restrict__ W2_0,
                       const float* __restrict__ Wf_0,
                       const float* __restrict__ W1_1, const float* __restrict__ W2_1,
                       const float* __restrict__ Wf_1,
                       const float* __restrict__ W_out,
                       uint4* __restrict__ Bp, uint4* __restrict__ Bc0,
                       uint4* __restrict__ Bc1, uint4* __restrict__ Bo) {
    int t = blockIdx.x * blockDim.x + threadIdx.x;
    const float* src;
    uint4* dst;
    if (t < 4096) {                       // W_in: 64 kb x 64 n
        int kb = t >> 6, n = t & 63;
        src = &W_in[n * FIN + kb * 8];
        dst = &Bp[t];
    } else if (t < 4096 + 1536) {         // layer 0
        int u = t - 4096;
        int j = u >> 9, kb = (u >> 6) & 7, n = u & 63;
        const float* W = (j == 0) ? W1_0 : (j == 1) ? W2_0 : Wf_0;
        src = &W[n * H + kb * 8];
        dst = &Bc0[u];
    } else if (t < 4096 + 3072) {         // layer 1
        int u = t - 4096 - 1536;
        int j = u >> 9, kb = (u >> 6) & 7, n = u & 63;
        const float* W = (j == 0) ? W1_1 : (j == 1) ? W2_1 : Wf_1;
        src = &W[n * H + kb * 8];
        dst = &Bc1[u];
    } else if (t < 4096 + 3072 + 512) {   // W_out: 8 kb x 64 cols (cols >= COUT -> 0)
        int u = t - 4096 - 3072;
        int kb = u >> 6, col = u & 63;
        if (col >= COUT) { Bo[u] = make_uint4(0u, 0u, 0u, 0u); return; }
        src = &W_out[col * H + kb * 8];
        dst = &Bo[u];
    } else return;
    float4 a0 = *(const float4*)&src[0];
    float4 a1 = *(const float4*)&src[4];
    uint4 u;
    u.x = ((unsigned)f2bf(a0.y) << 16) | f2bf(a0.x);
    u.y = ((unsigned)f2bf(a0.w) << 16) | f2bf(a0.z);
    u.z = ((unsigned)f2bf(a1.y) << 16) | f2bf(a1.x);
    u.w = ((unsigned)f2bf(a1.w) << 16) | f2bf(a1.z);
    *dst = u;
}

// ---------- CSR build ----------
__global__ void k_zero(int* __restrict__ p, int n) {
    int i = blockIdx.x * blockDim.x + threadIdx.x;
    if (i < n) p[i] = 0;
}

__global__ void k_hist(const int* __restrict__ ei, int* __restrict__ deg, int nE) {
    int e = blockIdx.x * blockDim.x + threadIdx.x;
    if (e < nE) atomicAdd(&deg[ei[nE + e]], 1);
}

__global__ __launch_bounds__(256) void k_scan1(const int* __restrict__ deg, int* __restrict__ epos,
                                               int* __restrict__ blocksum, int n) {
    __shared__ int tmp[256];
    int t = threadIdx.x;
    int base = blockIdx.x * 1024 + t * 4;
    int v[4]; int s = 0;
#pragma unroll
    for (int i = 0; i < 4; ++i) { v[i] = (base + i < n) ? deg[base + i] : 0; s += v[i]; }
    tmp[t] = s;
    __syncthreads();
    int incl = s;
    for (int off = 1; off < 256; off <<= 1) {
        int y = (t >= off) ? tmp[t - off] : 0;
        __syncthreads();
        incl += y;
        tmp[t] = incl;
        __syncthreads();
    }
    if (t == 255) blocksum[blockIdx.x] = incl;
    int run = incl - s;
#pragma unroll
    for (int i = 0; i < 4; ++i) { if (base + i < n) epos[base + i] = run; run += v[i]; }
}

__global__ __launch_bounds__(256) void k_scan2(const int* __restrict__ blocksum,
                                               int* __restrict__ blockoff, int nb) {
    __shared__ int tmp[256];
    int t = threadIdx.x;
    int s = (t < nb) ? blocksum[t] : 0;
    tmp[t] = s;
    __syncthreads();
    int incl = s;
    for (int off = 1; off < 256; off <<= 1) {
        int y = (t >= off) ? tmp[t - off] : 0;
        __syncthreads();
        incl += y;
        tmp[t] = incl;
        __syncthreads();
    }
    if (t < nb) blockoff[t] = incl - s;
}

__global__ __launch_bounds__(256) void k_scan3(int* __restrict__ epos, const int* __restrict__ blockoff,
                                               int* __restrict__ cursor, int n, int nE) {
    int b = blockIdx.x;
    int off = blockoff[b];
    int base = b * 1024 + threadIdx.x * 4;
#pragma unroll
    for (int i = 0; i < 4; ++i) {
        if (base + i < n) {
            int p = epos[base + i] + off;
            epos[base + i] = p;
            cursor[base + i] = p;
        }
    }
    if (b == 0 && threadIdx.x == 0) epos[n] = nE;
}

__global__ void k_scatter(const int* __restrict__ ei, int* __restrict__ cursor,
                          int* __restrict__ srcidx, int nE) {
    int e = blockIdx.x * blockDim.x + threadIdx.x;
    if (e < nE) {
        int c = ei[nE + e];
        int p = atomicAdd(&cursor[c], 1);
        srcidx[p] = ei[e];
    }
}

// ---------- Q(bf16) = x @ W_in^T + b_in  (bf16 MFMA, fp32 accumulate) ----------
__global__ __launch_bounds__(256) void k_in_gemm(
    const float* __restrict__ x, const uint4* __restrict__ Bp,
    const float* __restrict__ bias, unsigned short* __restrict__ qbf, int n) {
    __shared__ uint4 As4[256];
    __shared__ uint4 Bs4[256];
    int tid = threadIdx.x;
    int base = blockIdx.x * 64;
    int lane = tid & 63, w = tid >> 6;

    int srow = tid >> 2;
    int sg = tid & 3;
    int sgs = sg ^ ((srow >> 1) & 3);
    bool rowok = (base + srow) < n;
    const float* xsrc = &x[(size_t)(base + srow) * FIN + sg * 8];

    int arow = 16 * w + (lane & 15);
    int ag = (lane >> 4) ^ ((arow >> 1) & 3);
    int aidx = arow * 4 + ag;
    int kg = lane >> 4;

    f32x4 acc[4];
#pragma unroll
    for (int i = 0; i < 4; ++i) acc[i] = (f32x4){0.f, 0.f, 0.f, 0.f};

    for (int kk = 0; kk < FIN; kk += 32) {
        float4 a0 = make_float4(0.f, 0.f, 0.f, 0.f), a1 = a0;
        if (rowok) {
            a0 = *(const float4*)&xsrc[kk];
            a1 = *(const float4*)&xsrc[kk + 4];
        }
        uint4 bstage = Bp[((kk >> 3) + (tid >> 6)) * 64 + (tid & 63)];
        __syncthreads();
        {
            uint4 u;
            u.x = ((unsigned)f2bf(a0.y) << 16) | f2bf(a0.x);
            u.y = ((unsigned)f2bf(a0.w) << 16) | f2bf(a0.z);
            u.z = ((unsigned)f2bf(a1.y) << 16) | f2bf(a1.x);
            u.w = ((unsigned)f2bf(a1.w) << 16) | f2bf(a1.z);
            As4[srow * 4 + sgs] = u;
            Bs4[tid] = bstage;
        }
        __syncthreads();
        bf16x8 af = *(const bf16x8*)&As4[aidx];
#pragma unroll
        for (int nt = 0; nt < 4; ++nt) {
            bf16x8 bfr = *(const bf16x8*)&Bs4[kg * 64 + nt * 16 + (lane & 15)];
            acc[nt] = __builtin_amdgcn_mfma_f32_16x16x32_bf16(af, bfr, acc[nt], 0, 0, 0);
        }
    }
    int col0 = lane & 15, rowg = lane >> 4;
#pragma unroll
    for (int nt = 0; nt < 4; ++nt) {
        float bv = bias[nt * 16 + col0];
#pragma unroll
        for (int reg = 0; reg < 4; ++reg) {
            int r = base + 16 * w + rowg * 4 + reg;
            if (r < n) qbf[(size_t)r * H + nt * 16 + col0] = f2bf(acc[nt][reg] + bv);
        }
    }
}

// ---------- P = pack(bf16(Q@W1^T), bf16(Q@W2^T)), hl = bf16(relu(Q@Wf^T)) ----------
__global__ __launch_bounds__(256) void k_layer_gemm(
    const uint4* __restrict__ Qbf, const uint4* __restrict__ Bc,
    unsigned* __restrict__ P, unsigned short* __restrict__ hl, int n) {
    __shared__ uint4 Qs[512];
    int tid = threadIdx.x;
    int base = blockIdx.x * 64;
    int lane = tid & 63, w = tid >> 6;
    {
        int r = tid >> 2, g0 = (tid & 3) * 2;
        uint4 u0 = make_uint4(0u, 0u, 0u, 0u), u1 = u0;
        if (base + r < n) {
            u0 = Qbf[(size_t)(base + r) * 8 + g0];
            u1 = Qbf[(size_t)(base + r) * 8 + g0 + 1];
        }
        Qs[r * 8 + (g0 ^ (r & 7))] = u0;
        Qs[r * 8 + ((g0 + 1) ^ (r & 7))] = u1;
    }
    __syncthreads();

    int arow = w * 16 + (lane & 15);
    f32x4 acc[12];
#pragma unroll
    for (int i = 0; i < 12; ++i) acc[i] = (f32x4){0.f, 0.f, 0.f, 0.f};

#pragma unroll
    for (int ks = 0; ks < 2; ++ks) {
        int g = ks * 4 + (lane >> 4);
        bf16x8 af = *(const bf16x8*)&Qs[arow * 8 + (g ^ (arow & 7))];
#pragma unroll
        for (int j = 0; j < 3; ++j) {
#pragma unroll
            for (int nt = 0; nt < 4; ++nt) {
                bf16x8 bfr = *(const bf16x8*)&Bc[(j * 8 + g) * 64 + nt * 16 + (lane & 15)];
                acc[j * 4 + nt] = __builtin_amdgcn_mfma_f32_16x16x32_bf16(af, bfr, acc[j * 4 + nt], 0, 0, 0);
            }
        }
    }
    int col0 = lane & 15, rowg = lane >> 4;
#pragma unroll
    for (int nt = 0; nt < 4; ++nt) {
#pragma unroll
        for (int reg = 0; reg < 4; ++reg) {
            int r = base + w * 16 + rowg * 4 + reg;
            if (r < n) {
                int col = nt * 16 + col0;
                unsigned pv = ((unsigned)f2bf(acc[4 + nt][reg]) << 16) | f2bf(acc[nt][reg]);
                P[(size_t)r * H + col] = pv;
                hl[(size_t)r * H + col] = f2bf(fmaxf(acc[8 + nt][reg], 0.f));
            }
        }
    }
}

// ---------- CSR gather aggregation, 4 edges/iter, depth-3 pipeline ----------
// stage k: compute batch kb | stage k+1: row-gather batch kb+4 | stage k+2: srcidx batch kb+8
__global__ __launch_bounds__(256) void k_agg(
    const int* __restrict__ rowptr, const int* __restrict__ srcidx,
    const unsigned* __restrict__ P, const unsigned* __restrict__ hl32,
    unsigned* __restrict__ Qbf32, int n) {
    int tid = threadIdx.x;
    int lane = tid & 63;
    int w = tid >> 6;
    int c = blockIdx.x * 4 + w;
    if (c >= n) return;
    int q = lane >> 4;
    int j = lane & 15;
    const uint4* P4 = (const uint4*)P;

    uint4 pc = P4[(size_t)c * 16 + j];
    float4 h4c = make_float4(bfhi(pc.x), bfhi(pc.y), bfhi(pc.z), bfhi(pc.w));
    float4 acc = make_float4(0.f, 0.f, 0.f, 0.f);

    int k0 = rowptr[c], k1 = rowptr[c + 1];
    if (k0 < k1) {
        const uint4 Z = make_uint4(0u, 0u, 0u, 0u);
        int last = k1 - 1;
        int e0 = k0 + q;
        // prologue: srcidx for batches 0 and 1; gather batch 0
        int sA = srcidx[min(e0, last)];
        bool vA = e0 < k1;
        int sB = srcidx[min(e0 + 4, last)];
        bool vB = (e0 + 4) < k1;
        uint4 pA = P4[(size_t)sA * 16 + j];
        if (!vA) pA = Z;

        for (int kb = k0; kb < k1; kb += 4) {
            // stage k+2: srcidx for batch kb+8 (2 iterations ahead of its gather's use)
            int e2 = kb + 8 + q;
            int sC = srcidx[min(e2, last)];
            bool vC = e2 < k1;
            // stage k+1: gather rows for batch kb+4 (srcidx already in registers)
            uint4 pB = P4[(size_t)sB * 16 + j];
            if (!vB) pB = Z;
            // stage k: compute batch kb
            float4 h3r = make_float4(bflo(pA.x), bflo(pA.y), bflo(pA.z), bflo(pA.w));
            float4 h4r = make_float4(bfhi(pA.x), bfhi(pA.y), bfhi(pA.z), bfhi(pA.w));
            float d = h3r.x * h4c.x + h3r.y * h4c.y + h3r.z * h4c.z + h3r.w * h4c.w;
            d += __shfl_xor(d, 1, 64);
            d += __shfl_xor(d, 2, 64);
            d += __shfl_xor(d, 4, 64);
            d += __shfl_xor(d, 8, 64);
            float s = 1.0f / (1.0f + __expf(d));   // sigmoid(-d)
            float t = 1.0f - s;
            acc.x += s * h3r.x - t * h4r.x;
            acc.y += s * h3r.y - t * h4r.y;
            acc.z += s * h3r.z - t * h4r.z;
            acc.w += s * h3r.w - t * h4r.w;
            pA = pB; sB = sC; vB = vC;
        }
    }
    // sum across the 4 quarters
    acc.x += __shfl_xor(acc.x, 16, 64);
    acc.y += __shfl_xor(acc.y, 16, 64);
    acc.z += __shfl_xor(acc.z, 16, 64);
    acc.w += __shfl_xor(acc.w, 16, 64);
    acc.x += __shfl_xor(acc.x, 32, 64);
    acc.y += __shfl_xor(acc.y, 32, 64);
    acc.z += __shfl_xor(acc.z, 32, 64);
    acc.w += __shfl_xor(acc.w, 32, 64);

    uint2 hv = *(const uint2*)&hl32[(size_t)c * 32 + j * 2];
    acc.x += bflo(hv.x); acc.y += bfhi(hv.x);
    acc.z += bflo(hv.y); acc.w += bfhi(hv.y);

    float ss = acc.x * acc.x + acc.y * acc.y + acc.z * acc.z + acc.w * acc.w;
    ss += __shfl_xor(ss, 1, 64);
    ss += __shfl_xor(ss, 2, 64);
    ss += __shfl_xor(ss, 4, 64);
    ss += __shfl_xor(ss, 8, 64);
    float inv = 1.0f / fmaxf(sqrtf(ss), 1e-12f);

    if (lane < 16) {
        uint2 o;
        o.x = ((unsigned)f2bf(acc.y * inv) << 16) | f2bf(acc.x * inv);
        o.y = ((unsigned)f2bf(acc.w * inv) << 16) | f2bf(acc.z * inv);
        *(uint2*)&Qbf32[(size_t)c * 32 + j * 2] = o;
    }
}

// ---------- out = log_softmax(Q@W_out^T + b_out)  (bf16 MFMA head) ----------
__global__ __launch_bounds__(256) void k_head(
    const uint4* __restrict__ Qbf, const uint4* __restrict__ Bo,
    const float* __restrict__ b_out, float* __restrict__ out, int n) {
    __shared__ uint4 Qs[512];
    int tid = threadIdx.x;
    int base = blockIdx.x * 64;
    int lane = tid & 63, w = tid >> 6;
    {
        int r = tid >> 2, g0 = (tid & 3) * 2;
        uint4 u0 = make_uint4(0u, 0u, 0u, 0u), u1 = u0;
        if (base + r < n) {
            u0 = Qbf[(size_t)(base + r) * 8 + g0];
            u1 = Qbf[(size_t)(base + r) * 8 + g0 + 1];
        }
        Qs[r * 8 + (g0 ^ (r & 7))] = u0;
        Qs[r * 8 + ((g0 + 1) ^ (r & 7))] = u1;
    }
    __syncthreads();

    int arow = w * 16 + (lane & 15);
    f32x4 acc[3];
#pragma unroll
    for (int i = 0; i < 3; ++i) acc[i] = (f32x4){0.f, 0.f, 0.f, 0.f};
#pragma unroll
    for (int ks = 0; ks < 2; ++ks) {
        int g = ks * 4 + (lane >> 4);
        bf16x8 af = *(const bf16x8*)&Qs[arow * 8 + (g ^ (arow & 7))];
#pragma unroll
        for (int nt = 0; nt < 3; ++nt) {
            bf16x8 bfr = *(const bf16x8*)&Bo[g * 64 + nt * 16 + (lane & 15)];
            acc[nt] = __builtin_amdgcn_mfma_f32_16x16x32_bf16(af, bfr, acc[nt], 0, 0, 0);
        }
    }
    int col = lane & 15, rowg = lane >> 4;
    float bv0 = b_out[col];
    float bv1 = b_out[16 + col];
    float bv2 = (col < 8) ? b_out[32 + col] : 0.f;
#pragma unroll
    for (int reg = 0; reg < 4; ++reg) {
        int r = base + w * 16 + rowg * 4 + reg;
        float v0 = acc[0][reg] + bv0;
        float v1 = acc[1][reg] + bv1;
        float v2 = (col < 8) ? (acc[2][reg] + bv2) : -3.0e38f;
        float m = fmaxf(fmaxf(v0, v1), v2);
        m = fmaxf(m, __shfl_xor(m, 1, 64));
        m = fmaxf(m, __shfl_xor(m, 2, 64));
        m = fmaxf(m, __shfl_xor(m, 4, 64));
        m = fmaxf(m, __shfl_xor(m, 8, 64));
        float ex = __expf(v0 - m) + __expf(v1 - m) + ((col < 8) ? __expf(v2 - m) : 0.f);
        ex += __shfl_xor(ex, 1, 64);
        ex += __shfl_xor(ex, 2, 64);
        ex += __shfl_xor(ex, 4, 64);
        ex += __shfl_xor(ex, 8, 64);
        float lse = m + logf(ex);
        if (r < n) {
            out[(size_t)r * COUT + col] = v0 - lse;
            out[(size_t)r * COUT + 16 + col] = v1 - lse;
            if (col < 8) out[(size_t)r * COUT + 32 + col] = v2 - lse;
        }
    }
}

extern "C" void kernel_launch(void* const* d_in, const int* in_sizes, int n_in,
                              void* d_out, int out_size, void* d_ws, size_t ws_size,
                              hipStream_t stream) {
    const float* x     = (const float*)d_in[0];
    const int*   ei    = (const int*)d_in[1];
    const float* W_in  = (const float*)d_in[2];
    const float* b_in  = (const float*)d_in[3];
    const float* W1_0  = (const float*)d_in[4];
    const float* W2_0  = (const float*)d_in[5];
    const float* Wf_0  = (const float*)d_in[6];
    const float* W1_1  = (const float*)d_in[7];
    const float* W2_1  = (const float*)d_in[8];
    const float* Wf_1  = (const float*)d_in[9];
    const float* W_out = (const float*)d_in[10];
    const float* b_out = (const float*)d_in[11];
    float* out = (float*)d_out;

    int N = in_sizes[0] / FIN;
    int E = in_sizes[1] / 2;

    uint4* Bp    = (uint4*)d_ws;                     // 4096 uint4
    uint4* Bc0   = Bp + 4096;                        // 1536
    uint4* Bc1   = Bc0 + 1536;                       // 1536
    uint4* Bo    = Bc1 + 1536;                       // 512
    unsigned* Qbf32 = (unsigned*)(Bo + 512);         // N*32 u32 (bf16 Q)
    unsigned* P  = Qbf32 + (size_t)N * 32;           // N*64 u32 (packed h4|h3)
    unsigned* hl32 = P + (size_t)N * H;              // N*32 u32 (bf16 hloop)
    int* rowptr  = (int*)(hl32 + (size_t)N * 32);    // N+2
    int* deg     = rowptr + (N + 2);
    int* cursor  = deg + N;
    int* srcidx  = cursor + N;
    int* blocksum = srcidx + E;
    int* blockoff = blocksum + 256;

    k_pack<<<30, 256, 0, stream>>>(W_in, W1_0, W2_0, Wf_0, W1_1, W2_1, Wf_1, W_out,
                                   Bp, Bc0, Bc1, Bo);

    int nb = (N + 1023) / 1024;
    k_zero<<<(N + 255) / 256, 256, 0, stream>>>(deg, N);
    k_hist<<<(E + 255) / 256, 256, 0, stream>>>(ei, deg, E);
    k_scan1<<<nb, 256, 0, stream>>>(deg, rowptr, blocksum, N);
    k_scan2<<<1, 256, 0, stream>>>(blocksum, blockoff, nb);
    k_scan3<<<nb, 256, 0, stream>>>(rowptr, blockoff, cursor, N, E);
    k_scatter<<<(E + 255) / 256, 256, 0, stream>>>(ei, cursor, srcidx, E);

    int gm = (N + 63) / 64;
    k_in_gemm<<<gm, 256, 0, stream>>>(x, Bp, b_in, (unsigned short*)Qbf32, N);

    int ga = (N + 3) / 4;
    // layer 0
    k_layer_gemm<<<gm, 256, 0, stream>>>((const uint4*)Qbf32, Bc0, P, (unsigned short*)hl32, N);
    k_agg<<<ga, 256, 0, stream>>>(rowptr, srcidx, P, hl32, Qbf32, N);
    // layer 1
    k_layer_gemm<<<gm, 256, 0, stream>>>((const uint4*)Qbf32, Bc1, P, (unsigned short*)hl32, N);
    k_agg<<<ga, 256, 0, stream>>>(rowptr, srcidx, P, hl32, Qbf32, N);
    // output head
    k_head<<<gm, 256, 0, stream>>>((const uint4*)Qbf32, Bo, b_out, out, N);
}